// Round 3
// baseline (1154.341 us; speedup 1.0000x reference)
//
#include <hip/hip_runtime.h>
#include <hip/hip_bf16.h>

#define NB 2
#define NN 2048
#define ND 256
#define NS 16
#define NDC 4
#define NDI 512
#define NDTR 16

typedef __hip_bfloat16 bf16;

__device__ __forceinline__ float b2f(bf16 h) { return __bfloat162float(h); }

__device__ __forceinline__ void dec8(const uint4 u, float w[8]) {
    union { unsigned u; float f; } c;
    c.u = u.x << 16;          w[0] = c.f;
    c.u = u.x & 0xffff0000u;  w[1] = c.f;
    c.u = u.y << 16;          w[2] = c.f;
    c.u = u.y & 0xffff0000u;  w[3] = c.f;
    c.u = u.z << 16;          w[4] = c.f;
    c.u = u.z & 0xffff0000u;  w[5] = c.f;
    c.u = u.w << 16;          w[6] = c.f;
    c.u = u.w & 0xffff0000u;  w[7] = c.f;
}

// ---------------- K0a: detect input dtype (fp32 vs bf16) ----------------
// norm_w is all-ones. fp32 1.0f = 0x3F800000 (low16 == 0); bf16 pair = 0x3F803F80.
__global__ void k_detect(const unsigned* __restrict__ nw_raw, int* __restrict__ flag)
{
    if (threadIdx.x == 0 && blockIdx.x == 0) {
        unsigned v = nw_raw[0];
        flag[0] = ((v & 0xFFFFu) == 0u) ? 1 : 0;   // 1 = inputs are fp32
    }
}

// ---------------- K0b: convert/copy all inputs to bf16 in workspace ----------------
struct CvtArgs { const void* s[21]; };
// per-input element counts (d_in order) and destination offsets in cvt area (elements)
__device__ __constant__ const int seg_cnt[21] = {
    1048576, 1048576, 1048576, 768, 768, 786432, 6144, 1536, 73728,
    24576, 1536, 24576, 1536, 393216, 1, 196608, 256, 768, 3, 196608, 256 };
__device__ __constant__ const int seg_cum[22] = {
    0, 1048576, 2097152, 3145728, 3146496, 3147264, 3933696, 3939840,
    3941376, 4015104, 4039680, 4041216, 4065792, 4067328, 4460544, 4460545,
    4657153, 4657409, 4658177, 4658180, 4854788, 4855044 };
__device__ __constant__ const int seg_dst[21] = {
    0,        1048576,  2097152,  4847616, 4848384, 3145728, 4841472, 4849152, 4325376,
    4399104,  4850688,  4423680,  4852224, 3932160, 4855056, 4448256, 4853760, 4854016,
    4854784,  4644864,  4854800 };

__global__ __launch_bounds__(256) void k_convert(CvtArgs a, const int* __restrict__ flag,
                                                 bf16* __restrict__ dst)
{
    int idx = blockIdx.x * 256 + threadIdx.x;
    if (idx >= 4855044) return;
    int seg = 0;
    #pragma unroll
    for (int i = 1; i < 21; i++) if (idx >= seg_cum[i]) seg = i;
    int off = idx - seg_cum[seg];
    int f = flag[0];
    bf16 v;
    if (f) v = __float2bfloat16(((const float*)a.s[seg])[off]);
    else   v = ((const bf16*)a.s[seg])[off];
    dst[seg_dst[seg] + off] = v;
}

// ---------------- K1: layernorm per row -> xn (bf16) ----------------
__global__ __launch_bounds__(256) void k_layernorm(
    const bf16* __restrict__ e, const bf16* __restrict__ bl, const bf16* __restrict__ sp,
    const bf16* __restrict__ nw, const bf16* __restrict__ nb, bf16* __restrict__ xn)
{
    int row = blockIdx.x;            // sb*NN + n, sb = s*NB + b
    int sb = row >> 11, n = row & (NN - 1);
    int s = sb >> 1, b = sb & 1;
    const bf16* xin = (s == 0) ? e : ((s == 1) ? bl : sp);
    int t = threadIdx.x;
    float v = b2f(xin[((b << 11) + n) * ND + t]);
    float s1 = v, s2 = v * v;
    #pragma unroll
    for (int m = 1; m < 64; m <<= 1) { s1 += __shfl_xor(s1, m); s2 += __shfl_xor(s2, m); }
    __shared__ float r1[4], r2[4];
    int w = t >> 6;
    if ((t & 63) == 0) { r1[w] = s1; r2[w] = s2; }
    __syncthreads();
    float mean = (r1[0] + r1[1] + r1[2] + r1[3]) * (1.0f / ND);
    float ms   = (r2[0] + r2[1] + r2[2] + r2[3]) * (1.0f / ND);
    float inv = rsqrtf(ms - mean * mean + 1e-5f);
    float wv = b2f(nw[s * ND + t]), bv = b2f(nb[s * ND + t]);
    xn[row * ND + t] = __float2bfloat16((v - mean) * inv * wv + bv);
}

// ---------------- K2: in_proj GEMM -> xc, z (bf16) ----------------
__global__ __launch_bounds__(256) void k_inproj(
    const bf16* __restrict__ xn, const bf16* __restrict__ in_w,
    bf16* __restrict__ xc, bf16* __restrict__ z)
{
    __shared__ float xs[8][ND];
    int row0 = blockIdx.x * 8;
    int s = row0 / (NB * NN);
    int t = threadIdx.x;
    {   // 8 rows * 256 bf16 = 2048 bf16 = 256 uint4; one per thread
        uint4 u = ((const uint4*)(xn + (size_t)row0 * ND))[t];
        float w[8]; dec8(u, w);
        int r = t >> 5, col = (t & 31) * 8;
        #pragma unroll
        for (int j = 0; j < 8; j++) xs[r][col + j] = w[j];
    }
    __syncthreads();
    const bf16* W = in_w + (size_t)s * 2 * NDI * ND;
    for (int ee = 0; ee < 4; ee++) {
        int e = t + ee * 256;
        const uint4* wp = (const uint4*)(W + (size_t)e * ND);
        float a[8] = {0, 0, 0, 0, 0, 0, 0, 0};
        for (int k8 = 0; k8 < 32; k8++) {
            float w[8]; dec8(wp[k8], w);
            int k = k8 * 8;
            #pragma unroll
            for (int r = 0; r < 8; r++) {
                float4 x0 = *(const float4*)&xs[r][k];
                float4 x1 = *(const float4*)&xs[r][k + 4];
                a[r] += w[0] * x0.x + w[1] * x0.y + w[2] * x0.z + w[3] * x0.w
                      + w[4] * x1.x + w[5] * x1.y + w[6] * x1.z + w[7] * x1.w;
            }
        }
        bf16* dst = (e < NDI) ? xc : z;
        int ec = e & (NDI - 1);
        #pragma unroll
        for (int r = 0; r < 8; r++) dst[(size_t)(row0 + r) * NDI + ec] = __float2bfloat16(a[r]);
    }
}

// ---------------- K3: causal depthwise conv (DC=4) + silu -> xa (bf16) ----------------
__global__ __launch_bounds__(256) void k_conv(
    const bf16* __restrict__ xc, const bf16* __restrict__ conv_w,
    const bf16* __restrict__ conv_b, bf16* __restrict__ xa)
{
    int idx = blockIdx.x * 256 + threadIdx.x;   // over 6*2048*512
    int d = idx & (NDI - 1);
    int rn = idx >> 9;                          // sb*NN + n
    int n = rn & (NN - 1);
    int sb = rn >> 11;
    int s = sb >> 1;
    const bf16* cw = conv_w + ((size_t)s * NDI + d) * NDC;
    float w0 = b2f(cw[0]), w1 = b2f(cw[1]), w2 = b2f(cw[2]), w3 = b2f(cw[3]);
    float acc = b2f(conv_b[s * NDI + d]);
    acc += w3 * b2f(xc[idx]);
    if (n >= 1) acc += w2 * b2f(xc[idx - NDI]);
    if (n >= 2) acc += w1 * b2f(xc[idx - 2 * NDI]);
    if (n >= 3) acc += w0 * b2f(xc[idx - 3 * NDI]);
    xa[idx] = __float2bfloat16(acc / (1.0f + __expf(-acc)));
}

// ---------------- K4: x_proj (48 outs) + dt GEMM + softplus -> dt (bf16), Bm, Cm (fp32) ----------------
__global__ __launch_bounds__(256) void k_xproj(
    const bf16* __restrict__ xa, const bf16* __restrict__ xproj_w,
    const bf16* __restrict__ dt_w, const bf16* __restrict__ dt_b,
    bf16* __restrict__ dt, float* __restrict__ Bm, float* __restrict__ Cm)
{
    __shared__ float xr[4][NDI];
    __shared__ float xdbl[4][48];
    int row0 = blockIdx.x * 4;
    int s = row0 / (NB * NN);
    int t = threadIdx.x;
    {   // 4 rows * 512 bf16 = 2048 bf16 = 256 uint4; one per thread
        uint4 u = ((const uint4*)(xa + (size_t)row0 * NDI))[t];
        float w[8]; dec8(u, w);
        int r = t >> 6, col = (t & 63) * 8;
        #pragma unroll
        for (int j = 0; j < 8; j++) xr[r][col + j] = w[j];
    }
    __syncthreads();
    int wv = t >> 6, lane = t & 63;
    const bf16* XW = xproj_w + (size_t)s * 48 * NDI;
    for (int e = 0; e < 48; e++) {
        const uint4* wp = (const uint4*)(XW + (size_t)e * NDI);
        float w[8]; dec8(wp[lane], w);
        const float* xp = &xr[wv][lane * 8];
        float p = w[0] * xp[0] + w[1] * xp[1] + w[2] * xp[2] + w[3] * xp[3]
                + w[4] * xp[4] + w[5] * xp[5] + w[6] * xp[6] + w[7] * xp[7];
        #pragma unroll
        for (int m = 1; m < 64; m <<= 1) p += __shfl_xor(p, m);
        if (lane == 0) xdbl[wv][e] = p;
    }
    __syncthreads();
    for (int dd = 0; dd < 2; dd++) {
        int d = t + dd * 256;
        const uint4* wp = (const uint4*)(dt_w + ((size_t)s * NDI + d) * NDTR);
        float w[16]; dec8(wp[0], w); dec8(wp[1], w + 8);
        float bias = b2f(dt_b[s * NDI + d]);
        #pragma unroll
        for (int r = 0; r < 4; r++) {
            float a = bias;
            #pragma unroll
            for (int j = 0; j < 16; j++) a += w[j] * xdbl[r][j];
            a = (a > 20.0f) ? a : log1pf(__expf(a));   // softplus
            dt[(size_t)(row0 + r) * NDI + d] = __float2bfloat16(a);
        }
    }
    if (t < 128) {
        int r = t >> 5, j = t & 31;
        float vv = xdbl[r][16 + j];
        if (j < 16) Bm[(row0 + r) * NS + j] = vv;
        else        Cm[(row0 + r) * NS + (j - 16)] = vv;
    }
}

// ---------------- K5: selective scan + gating epilogue -> y (bf16) ----------------
// block = 16 channels x 16 states; grid = 6 sb * 32 channel-groups
__global__ __launch_bounds__(256) void k_scan(
    const bf16* __restrict__ dt, const bf16* __restrict__ xa, const bf16* __restrict__ z,
    const float* __restrict__ Bm, const float* __restrict__ Cm,
    const bf16* __restrict__ A_log, const bf16* __restrict__ Dp, bf16* __restrict__ y)
{
    __shared__ float dt_c[1024], xa_c[1024], z_c[1024], B_c[1024], C_c[1024], y_c[1024];
    int sb = blockIdx.x >> 5;
    int d0 = (blockIdx.x & 31) * 16;
    int s = sb >> 1;
    int t = threadIdx.x;
    int c = t >> 4, st = t & 15;
    int ch = d0 + c;
    float Aval = -__expf(b2f(A_log[((size_t)s * NDI + ch) * NS + st]));
    float Dpv = b2f(Dp[s * NDI + ch]);
    float h = 0.0f;
    const size_t rowbase = (size_t)sb * NN;
    for (int n0 = 0; n0 < NN; n0 += 64) {
        #pragma unroll
        for (int i = 0; i < 4; i++) {
            int li = i * 256 + t;
            int nl = li >> 4, cc = li & 15;
            size_t g = (rowbase + n0 + nl) * NDI + d0 + cc;
            dt_c[li] = b2f(dt[g]); xa_c[li] = b2f(xa[g]); z_c[li] = b2f(z[g]);
            size_t gb = (rowbase + n0) * NS + li;
            B_c[li] = Bm[gb]; C_c[li] = Cm[gb];
        }
        __syncthreads();
        for (int nl = 0; nl < 64; nl++) {
            float dtv = dt_c[nl * 16 + c];
            float xav = xa_c[nl * 16 + c];
            float bm = B_c[nl * 16 + st];
            float cm = C_c[nl * 16 + st];
            float dA = __expf(dtv * Aval);
            h = dA * h + dtv * bm * xav;
            float yp = h * cm;
            yp += __shfl_xor(yp, 1); yp += __shfl_xor(yp, 2);
            yp += __shfl_xor(yp, 4); yp += __shfl_xor(yp, 8);
            if (st == 0) {
                float yv = yp + xav * Dpv;
                float zv = z_c[nl * 16 + c];
                yv *= zv / (1.0f + __expf(-zv));
                y_c[nl * 16 + c] = yv;
            }
        }
        __syncthreads();
        #pragma unroll
        for (int i = 0; i < 4; i++) {
            int li = i * 256 + t;
            int nl = li >> 4, cc = li & 15;
            y[(rowbase + n0 + nl) * NDI + d0 + cc] = __float2bfloat16(y_c[li]);
        }
        __syncthreads();
    }
}

// ---------------- K6: out_proj + residual -> proc (bf16) ----------------
__global__ __launch_bounds__(256) void k_outproj(
    const bf16* __restrict__ y, const bf16* __restrict__ out_w,
    const bf16* __restrict__ e, const bf16* __restrict__ bl, const bf16* __restrict__ sp,
    bf16* __restrict__ proc)
{
    __shared__ float ys[8][NDI];
    int row0 = blockIdx.x * 8;
    int s = row0 / (NB * NN);
    int t = threadIdx.x;
    #pragma unroll
    for (int j = 0; j < 2; j++) {   // 8 rows * 512 bf16 = 512 uint4
        int li = j * 256 + t;
        uint4 u = ((const uint4*)(y + (size_t)row0 * NDI))[li];
        float w[8]; dec8(u, w);
        int r = li >> 6, col = (li & 63) * 8;
        #pragma unroll
        for (int q = 0; q < 8; q++) ys[r][col + q] = w[q];
    }
    __syncthreads();
    const uint4* wp = (const uint4*)(out_w + (size_t)s * ND * NDI + (size_t)t * NDI);
    float a[8] = {0, 0, 0, 0, 0, 0, 0, 0};
    for (int k8 = 0; k8 < 64; k8++) {
        float w[8]; dec8(wp[k8], w);
        int k = k8 * 8;
        #pragma unroll
        for (int r = 0; r < 8; r++) {
            float4 x0 = *(const float4*)&ys[r][k];
            float4 x1 = *(const float4*)&ys[r][k + 4];
            a[r] += w[0] * x0.x + w[1] * x0.y + w[2] * x0.z + w[3] * x0.w
                  + w[4] * x1.x + w[5] * x1.y + w[6] * x1.z + w[7] * x1.w;
        }
    }
    const bf16* xin = (s == 0) ? e : ((s == 1) ? bl : sp);
    int b = (row0 >> 11) & 1;
    int n = row0 & (NN - 1);
    #pragma unroll
    for (int r = 0; r < 8; r++) {
        proc[(size_t)(row0 + r) * ND + t] =
            __float2bfloat16(a[r] + b2f(xin[((b << 11) + n + r) * ND + t]));
    }
}

// ---------------- K7: mean-pool over N -> pooled (B,768) fp32 ----------------
__global__ __launch_bounds__(256) void k_pool(const bf16* __restrict__ proc, float* __restrict__ pooled)
{
    int e = blockIdx.x % 768, b = blockIdx.x / 768;
    int s = e >> 8, d = e & 255;
    const bf16* p = proc + ((size_t)(s * NB + b) * NN) * ND + d;
    float acc = 0.0f;
    for (int n = threadIdx.x; n < NN; n += 256) acc += b2f(p[(size_t)n * ND]);
    #pragma unroll
    for (int m = 1; m < 64; m <<= 1) acc += __shfl_xor(acc, m);
    __shared__ float r[4];
    if ((threadIdx.x & 63) == 0) r[threadIdx.x >> 6] = acc;
    __syncthreads();
    if (threadIdx.x == 0) pooled[b * 768 + e] = (r[0] + r[1] + r[2] + r[3]) * (1.0f / NN);
}

// ---------------- K8: gelu MLP + double softmax -> coeffs (B,3) fp32 ----------------
__global__ __launch_bounds__(256) void k_coeff(
    const float* __restrict__ pooled,
    const bf16* __restrict__ agg_w1, const bf16* __restrict__ agg_b1,
    const bf16* __restrict__ agg_w2, const bf16* __restrict__ agg_b2,
    const bf16* __restrict__ temp, float* __restrict__ coeffs)
{
    __shared__ float hb[256];
    __shared__ float lg[3];
    int t = threadIdx.x;
    for (int b = 0; b < NB; b++) {
        float a = b2f(agg_b1[t]);
        const uint4* wp = (const uint4*)(agg_w1 + (size_t)t * 768);
        for (int k8 = 0; k8 < 96; k8++) {
            float w[8]; dec8(wp[k8], w);
            const float* pp = pooled + b * 768 + k8 * 8;
            #pragma unroll
            for (int j = 0; j < 8; j++) a += w[j] * pp[j];
        }
        float x = a;
        float inner = 0.7978845608028654f * (x + 0.044715f * x * x * x);
        hb[t] = 0.5f * x * (1.0f + tanhf(inner));
        __syncthreads();
        if (t < 3) {
            float l = b2f(agg_b2[t]);
            const bf16* w2 = agg_w2 + t * 256;
            for (int d2 = 0; d2 < 256; d2++) l += b2f(w2[d2]) * hb[d2];
            lg[t] = l;
        }
        __syncthreads();
        if (t == 0) {
            float m = fmaxf(lg[0], fmaxf(lg[1], lg[2]));
            float e0 = __expf(lg[0] - m), e1 = __expf(lg[1] - m), e2 = __expf(lg[2] - m);
            float iS = 1.0f / (e0 + e1 + e2);
            float c0 = e0 * iS, c1 = e1 * iS, c2 = e2 * iS;
            float tt = b2f(temp[0]) + 1e-6f;
            float m2 = fmaxf(c0, fmaxf(c1, c2)) / tt;
            e0 = __expf(c0 / tt - m2); e1 = __expf(c1 / tt - m2); e2 = __expf(c2 / tt - m2);
            iS = 1.0f / (e0 + e1 + e2);
            coeffs[b * 3 + 0] = e0 * iS;
            coeffs[b * 3 + 1] = e1 * iS;
            coeffs[b * 3 + 2] = e2 * iS;
        }
        __syncthreads();
    }
}

// ---------------- K9: final proj + weighted residual -> d_out (bf16 or fp32) ----------------
__global__ __launch_bounds__(256) void k_final(
    const bf16* __restrict__ proc, const bf16* __restrict__ proj_w,
    const bf16* __restrict__ proj_b, const float* __restrict__ coeffs,
    const int* __restrict__ flag, void* __restrict__ out)
{
    __shared__ float mt[8][768];
    int row0 = blockIdx.x * 8;        // rows over B*N
    int b = row0 >> 11;
    int t = threadIdx.x;
    #pragma unroll
    for (int j = 0; j < 3; j++) {     // 8 rows * 768 bf16 = 768 uint4
        int li = j * 256 + t;
        int r = li / 96;              // 96 uint4 per row (768 bf16)
        int rem = li % 96;
        int s = rem / 32, q = rem % 32;   // 32 uint4 per 256-col stream segment
        int n = (row0 & (NN - 1)) + r;
        uint4 u = ((const uint4*)(proc + (((size_t)(s * NB + b) * NN) + n) * ND))[q];
        float w[8]; dec8(u, w);
        int col = s * 256 + q * 8;
        #pragma unroll
        for (int k = 0; k < 8; k++) mt[r][col + k] = w[k];
    }
    __syncthreads();
    float c0 = coeffs[b * 3], c1 = coeffs[b * 3 + 1], c2 = coeffs[b * 3 + 2];
    float pb = b2f(proj_b[t]);
    float a[8];
    #pragma unroll
    for (int r = 0; r < 8; r++)
        a[r] = pb + c0 * mt[r][t] + c1 * mt[r][256 + t] + c2 * mt[r][512 + t];
    const uint4* wp = (const uint4*)(proj_w + (size_t)t * 768);
    for (int k8 = 0; k8 < 96; k8++) {
        float w[8]; dec8(wp[k8], w);
        int k = k8 * 8;
        #pragma unroll
        for (int r = 0; r < 8; r++) {
            float4 x0 = *(const float4*)&mt[r][k];
            float4 x1 = *(const float4*)&mt[r][k + 4];
            a[r] += w[0] * x0.x + w[1] * x0.y + w[2] * x0.z + w[3] * x0.w
                  + w[4] * x1.x + w[5] * x1.y + w[6] * x1.z + w[7] * x1.w;
        }
    }
    if (flag[0]) {
        float* o = (float*)out;
        #pragma unroll
        for (int r = 0; r < 8; r++) o[(size_t)(row0 + r) * ND + t] = a[r];
    } else {
        bf16* o = (bf16*)out;
        #pragma unroll
        for (int r = 0; r < 8; r++) o[(size_t)(row0 + r) * ND + t] = __float2bfloat16(a[r]);
    }
}

extern "C" void kernel_launch(void* const* d_in, const int* in_sizes, int n_in,
                              void* d_out, int out_size, void* d_ws, size_t ws_size,
                              hipStream_t stream)
{
    // ---- workspace layout (bytes) ----
    char* w8 = (char*)d_ws;
    int*   flagp   = (int*)(w8);                    // 16 B
    bf16*  cvt     = (bf16*)(w8 + 16);              // 4,855,072 elems = 9,710,144 B
    bf16*  xn      = (bf16*)(w8 + 9710160);         // 3,145,728 elems (reused as proc)
    bf16*  xcb     = (bf16*)(w8 + 16001616);        // 6,291,456 elems (xc, then y)
    bf16*  zb      = (bf16*)(w8 + 28584528);
    bf16*  xab     = (bf16*)(w8 + 41167440);
    bf16*  dtb     = (bf16*)(w8 + 53750352);
    float* Bmb     = (float*)(w8 + 66333264);       // 196,608 f32
    float* Cmb     = (float*)(w8 + 67119696);
    float* pooledb = (float*)(w8 + 67906128);
    float* coeffsb = (float*)(w8 + 67912272);       // end ~67.9 MB
    bf16*  procb   = xn;                            // xn dead after k_inproj

    // converted-input pointers (element offsets must match seg_dst[])
    const bf16* c_edge   = cvt + 0;
    const bf16* c_blob   = cvt + 1048576;
    const bf16* c_spec   = cvt + 2097152;
    const bf16* c_inw    = cvt + 3145728;
    const bf16* c_outw   = cvt + 3932160;
    const bf16* c_xpw    = cvt + 4325376;
    const bf16* c_dtw    = cvt + 4399104;
    const bf16* c_alog   = cvt + 4423680;
    const bf16* c_agg1   = cvt + 4448256;
    const bf16* c_prjw   = cvt + 4644864;
    const bf16* c_convw  = cvt + 4841472;
    const bf16* c_nrmw   = cvt + 4847616;
    const bf16* c_nrmb   = cvt + 4848384;
    const bf16* c_convb  = cvt + 4849152;
    const bf16* c_dtb    = cvt + 4850688;
    const bf16* c_dp     = cvt + 4852224;
    const bf16* c_agb1   = cvt + 4853760;
    const bf16* c_agw2   = cvt + 4854016;
    const bf16* c_agb2   = cvt + 4854784;
    const bf16* c_prjb   = cvt + 4854800;
    const bf16* c_temp   = cvt + 4855056;

    k_detect<<<1, 64, 0, stream>>>((const unsigned*)d_in[3], flagp);
    CvtArgs ca;
    for (int i = 0; i < 21; i++) ca.s[i] = d_in[i];
    k_convert<<<(4855044 + 255) / 256, 256, 0, stream>>>(ca, flagp, cvt);

    k_layernorm<<<6 * NN, 256, 0, stream>>>(c_edge, c_blob, c_spec, c_nrmw, c_nrmb, xn);
    k_inproj<<<6 * NN / 8, 256, 0, stream>>>(xn, c_inw, xcb, zb);
    k_conv<<<6 * NN * NDI / 256, 256, 0, stream>>>(xcb, c_convw, c_convb, xab);
    k_xproj<<<6 * NN / 4, 256, 0, stream>>>(xab, c_xpw, c_dtw, c_dtb, dtb, Bmb, Cmb);
    k_scan<<<6 * 32, 256, 0, stream>>>(dtb, xab, zb, Bmb, Cmb, c_alog, c_dp, xcb);
    k_outproj<<<6 * NN / 8, 256, 0, stream>>>(xcb, c_outw, c_edge, c_blob, c_spec, procb);
    k_pool<<<NB * 768, 256, 0, stream>>>(procb, pooledb);
    k_coeff<<<1, 256, 0, stream>>>(pooledb, c_agg1, c_agb1, c_agw2, c_agb2, c_temp, coeffsb);
    k_final<<<NB * NN / 8, 256, 0, stream>>>(procb, c_prjw, c_prjb, coeffsb, flagp, d_out);
}

// Round 4
// 730.600 us; speedup vs baseline: 1.5800x; 1.5800x over previous
//
#include <hip/hip_runtime.h>
#include <hip/hip_bf16.h>

#define NB 2
#define NN 2048
#define ND 256
#define NS 16
#define NDC 4
#define NDI 512
#define NDTR 16
#define LCH 128   // chunk length for parallel scan
#define NCH 16    // number of chunks (LCH*NCH == NN)

typedef __hip_bfloat16 bf16;

__device__ __forceinline__ float b2f(bf16 h) { return __bfloat162float(h); }

__device__ __forceinline__ void dec8(const uint4 u, float w[8]) {
    union { unsigned u; float f; } c;
    c.u = u.x << 16;          w[0] = c.f;
    c.u = u.x & 0xffff0000u;  w[1] = c.f;
    c.u = u.y << 16;          w[2] = c.f;
    c.u = u.y & 0xffff0000u;  w[3] = c.f;
    c.u = u.z << 16;          w[4] = c.f;
    c.u = u.z & 0xffff0000u;  w[5] = c.f;
    c.u = u.w << 16;          w[6] = c.f;
    c.u = u.w & 0xffff0000u;  w[7] = c.f;
}

// ---------------- K0a: detect input dtype (fp32 vs bf16) ----------------
__global__ void k_detect(const unsigned* __restrict__ nw_raw, int* __restrict__ flag)
{
    if (threadIdx.x == 0 && blockIdx.x == 0) {
        unsigned v = nw_raw[0];
        flag[0] = ((v & 0xFFFFu) == 0u) ? 1 : 0;   // 1 = inputs are fp32
    }
}

// ---------------- K0b: convert/copy all inputs to bf16 in workspace ----------------
struct CvtArgs { const void* s[21]; };
__device__ __constant__ const int seg_cum[22] = {
    0, 1048576, 2097152, 3145728, 3146496, 3147264, 3933696, 3939840,
    3941376, 4015104, 4039680, 4041216, 4065792, 4067328, 4460544, 4460545,
    4657153, 4657409, 4658177, 4658180, 4854788, 4855044 };
__device__ __constant__ const int seg_dst[21] = {
    0,        1048576,  2097152,  4847616, 4848384, 3145728, 4841472, 4849152, 4325376,
    4399104,  4850688,  4423680,  4852224, 3932160, 4855056, 4448256, 4853760, 4854016,
    4854784,  4644864,  4854800 };

__global__ __launch_bounds__(256) void k_convert(CvtArgs a, const int* __restrict__ flag,
                                                 bf16* __restrict__ dst)
{
    int idx = blockIdx.x * 256 + threadIdx.x;
    if (idx >= 4855044) return;
    int seg = 0;
    #pragma unroll
    for (int i = 1; i < 21; i++) if (idx >= seg_cum[i]) seg = i;
    int off = idx - seg_cum[seg];
    int f = flag[0];
    bf16 v;
    if (f) v = __float2bfloat16(((const float*)a.s[seg])[off]);
    else   v = ((const bf16*)a.s[seg])[off];
    dst[seg_dst[seg] + off] = v;
}

// ---------------- K1: layernorm per row -> xn (bf16) ----------------
__global__ __launch_bounds__(256) void k_layernorm(
    const bf16* __restrict__ e, const bf16* __restrict__ bl, const bf16* __restrict__ sp,
    const bf16* __restrict__ nw, const bf16* __restrict__ nb, bf16* __restrict__ xn)
{
    int row = blockIdx.x;            // sb*NN + n, sb = s*NB + b
    int sb = row >> 11, n = row & (NN - 1);
    int s = sb >> 1, b = sb & 1;
    const bf16* xin = (s == 0) ? e : ((s == 1) ? bl : sp);
    int t = threadIdx.x;
    float v = b2f(xin[((b << 11) + n) * ND + t]);
    float s1 = v, s2 = v * v;
    #pragma unroll
    for (int m = 1; m < 64; m <<= 1) { s1 += __shfl_xor(s1, m); s2 += __shfl_xor(s2, m); }
    __shared__ float r1[4], r2[4];
    int w = t >> 6;
    if ((t & 63) == 0) { r1[w] = s1; r2[w] = s2; }
    __syncthreads();
    float mean = (r1[0] + r1[1] + r1[2] + r1[3]) * (1.0f / ND);
    float ms   = (r2[0] + r2[1] + r2[2] + r2[3]) * (1.0f / ND);
    float inv = rsqrtf(ms - mean * mean + 1e-5f);
    float wv = b2f(nw[s * ND + t]), bv = b2f(nb[s * ND + t]);
    xn[row * ND + t] = __float2bfloat16((v - mean) * inv * wv + bv);
}

// ---------------- K2: in_proj GEMM -> xc, z (bf16) ----------------
__global__ __launch_bounds__(256) void k_inproj(
    const bf16* __restrict__ xn, const bf16* __restrict__ in_w,
    bf16* __restrict__ xc, bf16* __restrict__ z)
{
    __shared__ float xs[8][ND];
    int row0 = blockIdx.x * 8;
    int s = row0 / (NB * NN);
    int t = threadIdx.x;
    {
        uint4 u = ((const uint4*)(xn + (size_t)row0 * ND))[t];
        float w[8]; dec8(u, w);
        int r = t >> 5, col = (t & 31) * 8;
        #pragma unroll
        for (int j = 0; j < 8; j++) xs[r][col + j] = w[j];
    }
    __syncthreads();
    const bf16* W = in_w + (size_t)s * 2 * NDI * ND;
    for (int ee = 0; ee < 4; ee++) {
        int e = t + ee * 256;
        const uint4* wp = (const uint4*)(W + (size_t)e * ND);
        float a[8] = {0, 0, 0, 0, 0, 0, 0, 0};
        for (int k8 = 0; k8 < 32; k8++) {
            float w[8]; dec8(wp[k8], w);
            int k = k8 * 8;
            #pragma unroll
            for (int r = 0; r < 8; r++) {
                float4 x0 = *(const float4*)&xs[r][k];
                float4 x1 = *(const float4*)&xs[r][k + 4];
                a[r] += w[0] * x0.x + w[1] * x0.y + w[2] * x0.z + w[3] * x0.w
                      + w[4] * x1.x + w[5] * x1.y + w[6] * x1.z + w[7] * x1.w;
            }
        }
        bf16* dst = (e < NDI) ? xc : z;
        int ec = e & (NDI - 1);
        #pragma unroll
        for (int r = 0; r < 8; r++) dst[(size_t)(row0 + r) * NDI + ec] = __float2bfloat16(a[r]);
    }
}

// ---------------- K3: causal depthwise conv (DC=4) + silu -> xa (bf16) ----------------
__global__ __launch_bounds__(256) void k_conv(
    const bf16* __restrict__ xc, const bf16* __restrict__ conv_w,
    const bf16* __restrict__ conv_b, bf16* __restrict__ xa)
{
    int idx = blockIdx.x * 256 + threadIdx.x;   // over 6*2048*512
    int d = idx & (NDI - 1);
    int rn = idx >> 9;                          // sb*NN + n
    int n = rn & (NN - 1);
    int sb = rn >> 11;
    int s = sb >> 1;
    const bf16* cw = conv_w + ((size_t)s * NDI + d) * NDC;
    float w0 = b2f(cw[0]), w1 = b2f(cw[1]), w2 = b2f(cw[2]), w3 = b2f(cw[3]);
    float acc = b2f(conv_b[s * NDI + d]);
    acc += w3 * b2f(xc[idx]);
    if (n >= 1) acc += w2 * b2f(xc[idx - NDI]);
    if (n >= 2) acc += w1 * b2f(xc[idx - 2 * NDI]);
    if (n >= 3) acc += w0 * b2f(xc[idx - 3 * NDI]);
    xa[idx] = __float2bfloat16(acc / (1.0f + __expf(-acc)));
}

// ---------------- K4: x_proj (48 outs) + dt GEMM + softplus -> dt (bf16), Bm, Cm (fp32) ----------------
__global__ __launch_bounds__(256) void k_xproj(
    const bf16* __restrict__ xa, const bf16* __restrict__ xproj_w,
    const bf16* __restrict__ dt_w, const bf16* __restrict__ dt_b,
    bf16* __restrict__ dt, float* __restrict__ Bm, float* __restrict__ Cm)
{
    __shared__ float xr[4][NDI];
    __shared__ float xdbl[4][48];
    int row0 = blockIdx.x * 4;
    int s = row0 / (NB * NN);
    int t = threadIdx.x;
    {
        uint4 u = ((const uint4*)(xa + (size_t)row0 * NDI))[t];
        float w[8]; dec8(u, w);
        int r = t >> 6, col = (t & 63) * 8;
        #pragma unroll
        for (int j = 0; j < 8; j++) xr[r][col + j] = w[j];
    }
    __syncthreads();
    int wv = t >> 6, lane = t & 63;
    const bf16* XW = xproj_w + (size_t)s * 48 * NDI;
    for (int e = 0; e < 48; e++) {
        const uint4* wp = (const uint4*)(XW + (size_t)e * NDI);
        float w[8]; dec8(wp[lane], w);
        const float* xp = &xr[wv][lane * 8];
        float p = w[0] * xp[0] + w[1] * xp[1] + w[2] * xp[2] + w[3] * xp[3]
                + w[4] * xp[4] + w[5] * xp[5] + w[6] * xp[6] + w[7] * xp[7];
        #pragma unroll
        for (int m = 1; m < 64; m <<= 1) p += __shfl_xor(p, m);
        if (lane == 0) xdbl[wv][e] = p;
    }
    __syncthreads();
    for (int dd = 0; dd < 2; dd++) {
        int d = t + dd * 256;
        const uint4* wp = (const uint4*)(dt_w + ((size_t)s * NDI + d) * NDTR);
        float w[16]; dec8(wp[0], w); dec8(wp[1], w + 8);
        float bias = b2f(dt_b[s * NDI + d]);
        #pragma unroll
        for (int r = 0; r < 4; r++) {
            float a = bias;
            #pragma unroll
            for (int j = 0; j < 16; j++) a += w[j] * xdbl[r][j];
            a = (a > 20.0f) ? a : log1pf(__expf(a));   // softplus
            dt[(size_t)(row0 + r) * NDI + d] = __float2bfloat16(a);
        }
    }
    if (t < 128) {
        int r = t >> 5, j = t & 31;
        float vv = xdbl[r][16 + j];
        if (j < 16) Bm[(row0 + r) * NS + j] = vv;
        else        Cm[(row0 + r) * NS + (j - 16)] = vv;
    }
}

// ---------------- K5a: chunk-local scan -> Hend, Pprod ----------------
// block = (sb, chunk, dgroup); thread = one channel; 16 states in registers.
__global__ __launch_bounds__(256) void k_scan1(
    const bf16* __restrict__ dt, const bf16* __restrict__ xa,
    const bf16* __restrict__ A_log, const float* __restrict__ Bm,
    float* __restrict__ Hend, float* __restrict__ Pprod)
{
    __shared__ float Bs[LCH * NS];
    int bid = blockIdx.x;                 // 6 * NCH * 2
    int sb = bid / (NCH * 2);
    int rem = bid % (NCH * 2);
    int chunk = rem >> 1, dg = rem & 1;
    int s = sb >> 1;
    int t = threadIdx.x;
    int d = dg * 256 + t;
    int n0 = chunk * LCH;
    size_t rowbase = (size_t)sb * NN;
    {   // stage B chunk: LCH*16 floats = 512 float4
        const float4* src = (const float4*)(Bm + (rowbase + n0) * NS);
        float4* dl = (float4*)Bs;
        dl[t] = src[t];
        dl[256 + t] = src[256 + t];
    }
    float A[16];
    {
        const uint4* ap = (const uint4*)(A_log + ((size_t)s * NDI + d) * NS);
        float al[8]; dec8(ap[0], al);
        #pragma unroll
        for (int i = 0; i < 8; i++) A[i] = -__expf(al[i]);
        dec8(ap[1], al);
        #pragma unroll
        for (int i = 0; i < 8; i++) A[8 + i] = -__expf(al[i]);
    }
    __syncthreads();
    float h[16], P[16];
    #pragma unroll
    for (int i = 0; i < 16; i++) { h[i] = 0.0f; P[i] = 1.0f; }
    const bf16* dtp = dt + (rowbase + n0) * NDI + d;
    const bf16* xap = xa + (rowbase + n0) * NDI + d;
    for (int nl = 0; nl < LCH; nl += 4) {
        float dtv[4], xav[4];
        #pragma unroll
        for (int j = 0; j < 4; j++) {
            dtv[j] = b2f(dtp[(size_t)(nl + j) * NDI]);
            xav[j] = b2f(xap[(size_t)(nl + j) * NDI]);
        }
        #pragma unroll
        for (int j = 0; j < 4; j++) {
            float bcom = dtv[j] * xav[j];
            const float4* br = (const float4*)&Bs[(nl + j) * NS];
            float4 b0 = br[0], b1 = br[1], b2 = br[2], b3 = br[3];
            float bv[16] = {b0.x,b0.y,b0.z,b0.w,b1.x,b1.y,b1.z,b1.w,
                            b2.x,b2.y,b2.z,b2.w,b3.x,b3.y,b3.z,b3.w};
            #pragma unroll
            for (int st = 0; st < 16; st++) {
                float dA = __expf(dtv[j] * A[st]);
                h[st] = dA * h[st] + bcom * bv[st];
                P[st] *= dA;
            }
        }
    }
    size_t base = ((size_t)(chunk * 6 + sb) * NS) * NDI + d;
    #pragma unroll
    for (int st = 0; st < 16; st++) {
        Hend[base + (size_t)st * NDI] = h[st];
        Pprod[base + (size_t)st * NDI] = P[st];
    }
}

// ---------------- K5b: serial prefix over chunk summaries (in place: Hend -> h_start) ----------------
__global__ __launch_bounds__(256) void k_scomb(float* __restrict__ Hend, const float* __restrict__ Pprod)
{
    int idx = blockIdx.x * 256 + threadIdx.x;   // 3072 = 6 sb * 512 d
    int sb = idx >> 9, d = idx & (NDI - 1);
    float h[16];
    #pragma unroll
    for (int i = 0; i < 16; i++) h[i] = 0.0f;
    for (int c = 0; c < NCH; c++) {
        size_t base = ((size_t)(c * 6 + sb) * NS) * NDI + d;
        #pragma unroll
        for (int st = 0; st < 16; st++) {
            size_t g = base + (size_t)st * NDI;
            float He = Hend[g], Pp = Pprod[g];
            Hend[g] = h[st];                 // h_start for this chunk
            h[st] = He + Pp * h[st];
        }
    }
}

// ---------------- K5c: re-scan chunks from h_start, C-dot + gating -> y (bf16) ----------------
__global__ __launch_bounds__(256) void k_scan2(
    const bf16* __restrict__ dt, const bf16* __restrict__ xa, const bf16* __restrict__ z,
    const float* __restrict__ Bm, const float* __restrict__ Cm,
    const bf16* __restrict__ A_log, const bf16* __restrict__ Dp,
    const float* __restrict__ Hstart, bf16* __restrict__ y)
{
    __shared__ float Bs[LCH * NS], Cs[LCH * NS];
    int bid = blockIdx.x;
    int sb = bid / (NCH * 2);
    int rem = bid % (NCH * 2);
    int chunk = rem >> 1, dg = rem & 1;
    int s = sb >> 1;
    int t = threadIdx.x;
    int d = dg * 256 + t;
    int n0 = chunk * LCH;
    size_t rowbase = (size_t)sb * NN;
    {
        const float4* srcB = (const float4*)(Bm + (rowbase + n0) * NS);
        const float4* srcC = (const float4*)(Cm + (rowbase + n0) * NS);
        float4* dB = (float4*)Bs; float4* dC = (float4*)Cs;
        dB[t] = srcB[t]; dB[256 + t] = srcB[256 + t];
        dC[t] = srcC[t]; dC[256 + t] = srcC[256 + t];
    }
    float A[16];
    {
        const uint4* ap = (const uint4*)(A_log + ((size_t)s * NDI + d) * NS);
        float al[8]; dec8(ap[0], al);
        #pragma unroll
        for (int i = 0; i < 8; i++) A[i] = -__expf(al[i]);
        dec8(ap[1], al);
        #pragma unroll
        for (int i = 0; i < 8; i++) A[8 + i] = -__expf(al[i]);
    }
    float Dpv = b2f(Dp[s * NDI + d]);
    float h[16];
    {
        size_t base = ((size_t)(chunk * 6 + sb) * NS) * NDI + d;
        #pragma unroll
        for (int st = 0; st < 16; st++) h[st] = Hstart[base + (size_t)st * NDI];
    }
    __syncthreads();
    const bf16* dtp = dt + (rowbase + n0) * NDI + d;
    const bf16* xap = xa + (rowbase + n0) * NDI + d;
    const bf16* zp  = z  + (rowbase + n0) * NDI + d;
    bf16* yp = y + (rowbase + n0) * NDI + d;
    for (int nl = 0; nl < LCH; nl += 4) {
        float dtv[4], xav[4], zv[4];
        #pragma unroll
        for (int j = 0; j < 4; j++) {
            dtv[j] = b2f(dtp[(size_t)(nl + j) * NDI]);
            xav[j] = b2f(xap[(size_t)(nl + j) * NDI]);
            zv[j]  = b2f(zp [(size_t)(nl + j) * NDI]);
        }
        #pragma unroll
        for (int j = 0; j < 4; j++) {
            float bcom = dtv[j] * xav[j];
            const float4* br = (const float4*)&Bs[(nl + j) * NS];
            const float4* cr = (const float4*)&Cs[(nl + j) * NS];
            float4 b0 = br[0], b1 = br[1], b2 = br[2], b3 = br[3];
            float4 c0 = cr[0], c1 = cr[1], c2 = cr[2], c3 = cr[3];
            float bv[16] = {b0.x,b0.y,b0.z,b0.w,b1.x,b1.y,b1.z,b1.w,
                            b2.x,b2.y,b2.z,b2.w,b3.x,b3.y,b3.z,b3.w};
            float cv[16] = {c0.x,c0.y,c0.z,c0.w,c1.x,c1.y,c1.z,c1.w,
                            c2.x,c2.y,c2.z,c2.w,c3.x,c3.y,c3.z,c3.w};
            float yacc = 0.0f;
            #pragma unroll
            for (int st = 0; st < 16; st++) {
                float dA = __expf(dtv[j] * A[st]);
                h[st] = dA * h[st] + bcom * bv[st];
                yacc += h[st] * cv[st];
            }
            float yv = yacc + xav[j] * Dpv;
            float zz = zv[j];
            yv *= zz / (1.0f + __expf(-zz));
            yp[(size_t)(nl + j) * NDI] = __float2bfloat16(yv);
        }
    }
}

// ---------------- K6: out_proj + residual -> proc (bf16) ----------------
__global__ __launch_bounds__(256) void k_outproj(
    const bf16* __restrict__ y, const bf16* __restrict__ out_w,
    const bf16* __restrict__ e, const bf16* __restrict__ bl, const bf16* __restrict__ sp,
    bf16* __restrict__ proc)
{
    __shared__ float ys[8][NDI];
    int row0 = blockIdx.x * 8;
    int s = row0 / (NB * NN);
    int t = threadIdx.x;
    #pragma unroll
    for (int j = 0; j < 2; j++) {   // 8 rows * 512 bf16 = 512 uint4
        int li = j * 256 + t;
        uint4 u = ((const uint4*)(y + (size_t)row0 * NDI))[li];
        float w[8]; dec8(u, w);
        int r = li >> 6, col = (li & 63) * 8;
        #pragma unroll
        for (int q = 0; q < 8; q++) ys[r][col + q] = w[q];
    }
    __syncthreads();
    const uint4* wp = (const uint4*)(out_w + (size_t)s * ND * NDI + (size_t)t * NDI);
    float a[8] = {0, 0, 0, 0, 0, 0, 0, 0};
    for (int k8 = 0; k8 < 64; k8++) {
        float w[8]; dec8(wp[k8], w);
        int k = k8 * 8;
        #pragma unroll
        for (int r = 0; r < 8; r++) {
            float4 x0 = *(const float4*)&ys[r][k];
            float4 x1 = *(const float4*)&ys[r][k + 4];
            a[r] += w[0] * x0.x + w[1] * x0.y + w[2] * x0.z + w[3] * x0.w
                  + w[4] * x1.x + w[5] * x1.y + w[6] * x1.z + w[7] * x1.w;
        }
    }
    const bf16* xin = (s == 0) ? e : ((s == 1) ? bl : sp);
    int b = (row0 >> 11) & 1;
    int n = row0 & (NN - 1);
    #pragma unroll
    for (int r = 0; r < 8; r++) {
        proc[(size_t)(row0 + r) * ND + t] =
            __float2bfloat16(a[r] + b2f(xin[((b << 11) + n + r) * ND + t]));
    }
}

// ---------------- K7: mean-pool over N -> pooled (B,768) fp32 ----------------
__global__ __launch_bounds__(256) void k_pool(const bf16* __restrict__ proc, float* __restrict__ pooled)
{
    int e = blockIdx.x % 768, b = blockIdx.x / 768;
    int s = e >> 8, d = e & 255;
    const bf16* p = proc + ((size_t)(s * NB + b) * NN) * ND + d;
    float acc = 0.0f;
    for (int n = threadIdx.x; n < NN; n += 256) acc += b2f(p[(size_t)n * ND]);
    #pragma unroll
    for (int m = 1; m < 64; m <<= 1) acc += __shfl_xor(acc, m);
    __shared__ float r[4];
    if ((threadIdx.x & 63) == 0) r[threadIdx.x >> 6] = acc;
    __syncthreads();
    if (threadIdx.x == 0) pooled[b * 768 + e] = (r[0] + r[1] + r[2] + r[3]) * (1.0f / NN);
}

// ---------------- K8: gelu MLP + double softmax -> coeffs (B,3) fp32 ----------------
__global__ __launch_bounds__(256) void k_coeff(
    const float* __restrict__ pooled,
    const bf16* __restrict__ agg_w1, const bf16* __restrict__ agg_b1,
    const bf16* __restrict__ agg_w2, const bf16* __restrict__ agg_b2,
    const bf16* __restrict__ temp, float* __restrict__ coeffs)
{
    __shared__ float hb[256];
    __shared__ float lg[3];
    int t = threadIdx.x;
    for (int b = 0; b < NB; b++) {
        float a = b2f(agg_b1[t]);
        const uint4* wp = (const uint4*)(agg_w1 + (size_t)t * 768);
        for (int k8 = 0; k8 < 96; k8++) {
            float w[8]; dec8(wp[k8], w);
            const float* pp = pooled + b * 768 + k8 * 8;
            #pragma unroll
            for (int j = 0; j < 8; j++) a += w[j] * pp[j];
        }
        float x = a;
        float inner = 0.7978845608028654f * (x + 0.044715f * x * x * x);
        hb[t] = 0.5f * x * (1.0f + tanhf(inner));
        __syncthreads();
        if (t < 3) {
            float l = b2f(agg_b2[t]);
            const bf16* w2 = agg_w2 + t * 256;
            for (int d2 = 0; d2 < 256; d2++) l += b2f(w2[d2]) * hb[d2];
            lg[t] = l;
        }
        __syncthreads();
        if (t == 0) {
            float m = fmaxf(lg[0], fmaxf(lg[1], lg[2]));
            float e0 = __expf(lg[0] - m), e1 = __expf(lg[1] - m), e2 = __expf(lg[2] - m);
            float iS = 1.0f / (e0 + e1 + e2);
            float c0 = e0 * iS, c1 = e1 * iS, c2 = e2 * iS;
            float tt = b2f(temp[0]) + 1e-6f;
            float m2 = fmaxf(c0, fmaxf(c1, c2)) / tt;
            e0 = __expf(c0 / tt - m2); e1 = __expf(c1 / tt - m2); e2 = __expf(c2 / tt - m2);
            iS = 1.0f / (e0 + e1 + e2);
            coeffs[b * 3 + 0] = e0 * iS;
            coeffs[b * 3 + 1] = e1 * iS;
            coeffs[b * 3 + 2] = e2 * iS;
        }
        __syncthreads();
    }
}

// ---------------- K9: final proj + weighted residual -> d_out (bf16 or fp32) ----------------
__global__ __launch_bounds__(256) void k_final(
    const bf16* __restrict__ proc, const bf16* __restrict__ proj_w,
    const bf16* __restrict__ proj_b, const float* __restrict__ coeffs,
    const int* __restrict__ flag, void* __restrict__ out)
{
    __shared__ float mt[8][768];
    int row0 = blockIdx.x * 8;        // rows over B*N
    int b = row0 >> 11;
    int t = threadIdx.x;
    #pragma unroll
    for (int j = 0; j < 3; j++) {     // 8 rows * 768 bf16 = 768 uint4
        int li = j * 256 + t;
        int r = li / 96;
        int rem = li % 96;
        int s = rem / 32, q = rem % 32;
        int n = (row0 & (NN - 1)) + r;
        uint4 u = ((const uint4*)(proc + (((size_t)(s * NB + b) * NN) + n) * ND))[q];
        float w[8]; dec8(u, w);
        int col = s * 256 + q * 8;
        #pragma unroll
        for (int k = 0; k < 8; k++) mt[r][col + k] = w[k];
    }
    __syncthreads();
    float c0 = coeffs[b * 3], c1 = coeffs[b * 3 + 1], c2 = coeffs[b * 3 + 2];
    float pb = b2f(proj_b[t]);
    float a[8];
    #pragma unroll
    for (int r = 0; r < 8; r++)
        a[r] = pb + c0 * mt[r][t] + c1 * mt[r][256 + t] + c2 * mt[r][512 + t];
    const uint4* wp = (const uint4*)(proj_w + (size_t)t * 768);
    for (int k8 = 0; k8 < 96; k8++) {
        float w[8]; dec8(wp[k8], w);
        int k = k8 * 8;
        #pragma unroll
        for (int r = 0; r < 8; r++) {
            float4 x0 = *(const float4*)&mt[r][k];
            float4 x1 = *(const float4*)&mt[r][k + 4];
            a[r] += w[0] * x0.x + w[1] * x0.y + w[2] * x0.z + w[3] * x0.w
                  + w[4] * x1.x + w[5] * x1.y + w[6] * x1.z + w[7] * x1.w;
        }
    }
    if (flag[0]) {
        float* o = (float*)out;
        #pragma unroll
        for (int r = 0; r < 8; r++) o[(size_t)(row0 + r) * ND + t] = a[r];
    } else {
        bf16* o = (bf16*)out;
        #pragma unroll
        for (int r = 0; r < 8; r++) o[(size_t)(row0 + r) * ND + t] = __float2bfloat16(a[r]);
    }
}

extern "C" void kernel_launch(void* const* d_in, const int* in_sizes, int n_in,
                              void* d_out, int out_size, void* d_ws, size_t ws_size,
                              hipStream_t stream)
{
    // ---- workspace layout (bytes), total ~74.2 MB ----
    char* w8 = (char*)d_ws;
    int*   flagp   = (int*)(w8);                    // 16 B
    bf16*  cvt     = (bf16*)(w8 + 16);              // 9,710,144 B
    bf16*  xn      = (bf16*)(w8 + 9710160);         // 6,291,456 B (reused as proc)
    bf16*  xcb     = (bf16*)(w8 + 16001616);        // 12,582,912 B (xc, then y)
    bf16*  zb      = (bf16*)(w8 + 28584528);
    bf16*  xab     = (bf16*)(w8 + 41167440);
    bf16*  dtb     = (bf16*)(w8 + 53750352);
    float* Bmb     = (float*)(w8 + 66333264);       // 786,432 B
    float* Cmb     = (float*)(w8 + 67119696);       // 786,432 B
    float* pooledb = (float*)(w8 + 67906128);       // 6,144 B
    float* coeffsb = (float*)(w8 + 67912272);       // 24 B
    float* Hendb   = (float*)(w8 + 67912304);       // 786,432 f32 = 3,145,728 B (then h_start)
    float* Pprodb  = (float*)(w8 + 71058032);       // 3,145,728 B -> end 74,203,760
    bf16*  procb   = xn;                            // xn dead after k_inproj

    const bf16* c_edge   = cvt + 0;
    const bf16* c_blob   = cvt + 1048576;
    const bf16* c_spec   = cvt + 2097152;
    const bf16* c_inw    = cvt + 3145728;
    const bf16* c_outw   = cvt + 3932160;
    const bf16* c_xpw    = cvt + 4325376;
    const bf16* c_dtw    = cvt + 4399104;
    const bf16* c_alog   = cvt + 4423680;
    const bf16* c_agg1   = cvt + 4448256;
    const bf16* c_prjw   = cvt + 4644864;
    const bf16* c_convw  = cvt + 4841472;
    const bf16* c_nrmw   = cvt + 4847616;
    const bf16* c_nrmb   = cvt + 4848384;
    const bf16* c_convb  = cvt + 4849152;
    const bf16* c_dtb    = cvt + 4850688;
    const bf16* c_dp     = cvt + 4852224;
    const bf16* c_agb1   = cvt + 4853760;
    const bf16* c_agw2   = cvt + 4854016;
    const bf16* c_agb2   = cvt + 4854784;
    const bf16* c_prjb   = cvt + 4854800;
    const bf16* c_temp   = cvt + 4855056;

    k_detect<<<1, 64, 0, stream>>>((const unsigned*)d_in[3], flagp);
    CvtArgs ca;
    for (int i = 0; i < 21; i++) ca.s[i] = d_in[i];
    k_convert<<<(4855044 + 255) / 256, 256, 0, stream>>>(ca, flagp, cvt);

    k_layernorm<<<6 * NN, 256, 0, stream>>>(c_edge, c_blob, c_spec, c_nrmw, c_nrmb, xn);
    k_inproj<<<6 * NN / 8, 256, 0, stream>>>(xn, c_inw, xcb, zb);
    k_conv<<<6 * NN * NDI / 256, 256, 0, stream>>>(xcb, c_convw, c_convb, xab);
    k_xproj<<<6 * NN / 4, 256, 0, stream>>>(xab, c_xpw, c_dtw, c_dtb, dtb, Bmb, Cmb);
    k_scan1<<<6 * NCH * 2, 256, 0, stream>>>(dtb, xab, c_alog, Bmb, Hendb, Pprodb);
    k_scomb<<<12, 256, 0, stream>>>(Hendb, Pprodb);
    k_scan2<<<6 * NCH * 2, 256, 0, stream>>>(dtb, xab, zb, Bmb, Cmb, c_alog, c_dp, Hendb, xcb);
    k_outproj<<<6 * NN / 8, 256, 0, stream>>>(xcb, c_outw, c_edge, c_blob, c_spec, procb);
    k_pool<<<NB * 768, 256, 0, stream>>>(procb, pooledb);
    k_coeff<<<1, 256, 0, stream>>>(pooledb, c_agg1, c_agb1, c_agw2, c_agb2, c_temp, coeffsb);
    k_final<<<NB * NN / 8, 256, 0, stream>>>(procb, c_prjw, c_prjb, coeffsb, flagp, d_out);
}

// Round 5
// 449.403 us; speedup vs baseline: 2.5686x; 1.6257x over previous
//
#include <hip/hip_runtime.h>
#include <hip/hip_bf16.h>

#define NB 2
#define NN 2048
#define ND 256
#define NS 16
#define NDC 4
#define NDI 512
#define NDTR 16
#define LCH 128   // chunk length for parallel scan
#define NCH 16    // number of chunks (LCH*NCH == NN)

typedef __hip_bfloat16 bf16;
typedef __attribute__((ext_vector_type(8))) __bf16 bf16x8;
typedef __attribute__((ext_vector_type(4))) float f32x4;

__device__ __forceinline__ float b2f(bf16 h) { return __bfloat162float(h); }

__device__ __forceinline__ void dec8(const uint4 u, float w[8]) {
    union { unsigned u; float f; } c;
    c.u = u.x << 16;          w[0] = c.f;
    c.u = u.x & 0xffff0000u;  w[1] = c.f;
    c.u = u.y << 16;          w[2] = c.f;
    c.u = u.y & 0xffff0000u;  w[3] = c.f;
    c.u = u.z << 16;          w[4] = c.f;
    c.u = u.z & 0xffff0000u;  w[5] = c.f;
    c.u = u.w << 16;          w[6] = c.f;
    c.u = u.w & 0xffff0000u;  w[7] = c.f;
}

// ---------------- K0a: detect input dtype (fp32 vs bf16) ----------------
__global__ void k_detect(const unsigned* __restrict__ nw_raw, int* __restrict__ flag)
{
    if (threadIdx.x == 0 && blockIdx.x == 0) {
        unsigned v = nw_raw[0];
        flag[0] = ((v & 0xFFFFu) == 0u) ? 1 : 0;   // 1 = inputs are fp32
    }
}

// ---------------- K0b: convert/copy all inputs to bf16 in workspace ----------------
struct CvtArgs { const void* s[21]; };
__device__ __constant__ const int seg_cum[22] = {
    0, 1048576, 2097152, 3145728, 3146496, 3147264, 3933696, 3939840,
    3941376, 4015104, 4039680, 4041216, 4065792, 4067328, 4460544, 4460545,
    4657153, 4657409, 4658177, 4658180, 4854788, 4855044 };
__device__ __constant__ const int seg_dst[21] = {
    0,        1048576,  2097152,  4847616, 4848384, 3145728, 4841472, 4849152, 4325376,
    4399104,  4850688,  4423680,  4852224, 3932160, 4855056, 4448256, 4853760, 4854016,
    4854784,  4644864,  4854800 };

__global__ __launch_bounds__(256) void k_convert(CvtArgs a, const int* __restrict__ flag,
                                                 bf16* __restrict__ dst)
{
    int idx = blockIdx.x * 256 + threadIdx.x;
    if (idx >= 4855044) return;
    int seg = 0;
    #pragma unroll
    for (int i = 1; i < 21; i++) if (idx >= seg_cum[i]) seg = i;
    int off = idx - seg_cum[seg];
    int f = flag[0];
    bf16 v;
    if (f) v = __float2bfloat16(((const float*)a.s[seg])[off]);
    else   v = ((const bf16*)a.s[seg])[off];
    dst[seg_dst[seg] + off] = v;
}

// ---------------- K1: layernorm per row -> xn (bf16) ----------------
__global__ __launch_bounds__(256) void k_layernorm(
    const bf16* __restrict__ e, const bf16* __restrict__ bl, const bf16* __restrict__ sp,
    const bf16* __restrict__ nw, const bf16* __restrict__ nb, bf16* __restrict__ xn)
{
    int row = blockIdx.x;            // sb*NN + n, sb = s*NB + b
    int sb = row >> 11, n = row & (NN - 1);
    int s = sb >> 1, b = sb & 1;
    const bf16* xin = (s == 0) ? e : ((s == 1) ? bl : sp);
    int t = threadIdx.x;
    float v = b2f(xin[((b << 11) + n) * ND + t]);
    float s1 = v, s2 = v * v;
    #pragma unroll
    for (int m = 1; m < 64; m <<= 1) { s1 += __shfl_xor(s1, m); s2 += __shfl_xor(s2, m); }
    __shared__ float r1[4], r2[4];
    int w = t >> 6;
    if ((t & 63) == 0) { r1[w] = s1; r2[w] = s2; }
    __syncthreads();
    float mean = (r1[0] + r1[1] + r1[2] + r1[3]) * (1.0f / ND);
    float ms   = (r2[0] + r2[1] + r2[2] + r2[3]) * (1.0f / ND);
    float inv = rsqrtf(ms - mean * mean + 1e-5f);
    float wv = b2f(nw[s * ND + t]), bv = b2f(nb[s * ND + t]);
    xn[row * ND + t] = __float2bfloat16((v - mean) * inv * wv + bv);
}

// ---------------- K2: in_proj GEMM (MFMA) -> xc, z (bf16) ----------------
// wave: 16m x 64e strip; grid 192 m-blocks x 16 e-blocks
__global__ __launch_bounds__(256) void k_inproj_mfma(
    const bf16* __restrict__ xn, const bf16* __restrict__ in_w,
    bf16* __restrict__ xc, bf16* __restrict__ z)
{
    int bid = blockIdx.x;
    int bm = bid >> 4, be = bid & 15;
    int t = threadIdx.x;
    int w = t >> 6, l = t & 63;
    int quad = l >> 4, lan = l & 15;
    int m0 = bm * 64 + w * 16;
    int e0 = be * 64;
    int s = m0 >> 12;
    const bf16* W = in_w + (size_t)s * (2 * NDI) * ND;
    f32x4 acc[4];
    #pragma unroll
    for (int j = 0; j < 4; j++) acc[j] = (f32x4){0.f, 0.f, 0.f, 0.f};
    const bf16* arow = xn + (size_t)(m0 + lan) * ND + quad * 8;
    const bf16* brow = W + (size_t)(e0 + lan) * ND + quad * 8;
    #pragma unroll 2
    for (int kk = 0; kk < 8; kk++) {
        bf16x8 a = *(const bf16x8*)(arow + kk * 32);
        #pragma unroll
        for (int j = 0; j < 4; j++) {
            bf16x8 b = *(const bf16x8*)(brow + (size_t)j * 16 * ND + kk * 32);
            acc[j] = __builtin_amdgcn_mfma_f32_16x16x32_bf16(a, b, acc[j], 0, 0, 0);
        }
    }
    #pragma unroll
    for (int j = 0; j < 4; j++) {
        int e = e0 + j * 16 + lan;
        bf16* dst = (e < NDI) ? xc : z;
        int ec = e & (NDI - 1);
        #pragma unroll
        for (int r = 0; r < 4; r++) {
            int m = m0 + quad * 4 + r;
            dst[(size_t)m * NDI + ec] = __float2bfloat16(acc[j][r]);
        }
    }
}

// ---------------- K3: causal depthwise conv (DC=4) + silu -> xa (bf16) ----------------
__global__ __launch_bounds__(256) void k_conv(
    const bf16* __restrict__ xc, const bf16* __restrict__ conv_w,
    const bf16* __restrict__ conv_b, bf16* __restrict__ xa)
{
    int idx = blockIdx.x * 256 + threadIdx.x;   // over 6*2048*512
    int d = idx & (NDI - 1);
    int rn = idx >> 9;                          // sb*NN + n
    int n = rn & (NN - 1);
    int sb = rn >> 11;
    int s = sb >> 1;
    const bf16* cw = conv_w + ((size_t)s * NDI + d) * NDC;
    float w0 = b2f(cw[0]), w1 = b2f(cw[1]), w2 = b2f(cw[2]), w3 = b2f(cw[3]);
    float acc = b2f(conv_b[s * NDI + d]);
    acc += w3 * b2f(xc[idx]);
    if (n >= 1) acc += w2 * b2f(xc[idx - NDI]);
    if (n >= 2) acc += w1 * b2f(xc[idx - 2 * NDI]);
    if (n >= 3) acc += w0 * b2f(xc[idx - 3 * NDI]);
    xa[idx] = __float2bfloat16(acc / (1.0f + __expf(-acc)));
}

// ---------------- K4a: x_proj GEMM (MFMA) -> xdbl fp32 [12288][48] ----------------
// wave: 16m x 48e; grid 192 blocks (4 waves = 64 rows each)
__global__ __launch_bounds__(256) void k_xproj_mfma(
    const bf16* __restrict__ xa, const bf16* __restrict__ xproj_w,
    float* __restrict__ xdbl)
{
    int bid = blockIdx.x;
    int t = threadIdx.x;
    int w = t >> 6, l = t & 63;
    int quad = l >> 4, lan = l & 15;
    int m0 = bid * 64 + w * 16;
    int s = m0 >> 12;
    const bf16* W = xproj_w + (size_t)s * 48 * NDI;
    f32x4 acc[3];
    #pragma unroll
    for (int j = 0; j < 3; j++) acc[j] = (f32x4){0.f, 0.f, 0.f, 0.f};
    const bf16* arow = xa + (size_t)(m0 + lan) * NDI + quad * 8;
    const bf16* brow = W + (size_t)lan * NDI + quad * 8;
    #pragma unroll 2
    for (int kk = 0; kk < 16; kk++) {
        bf16x8 a = *(const bf16x8*)(arow + kk * 32);
        #pragma unroll
        for (int j = 0; j < 3; j++) {
            bf16x8 b = *(const bf16x8*)(brow + (size_t)j * 16 * NDI + kk * 32);
            acc[j] = __builtin_amdgcn_mfma_f32_16x16x32_bf16(a, b, acc[j], 0, 0, 0);
        }
    }
    #pragma unroll
    for (int j = 0; j < 3; j++) {
        int e = j * 16 + lan;
        #pragma unroll
        for (int r = 0; r < 4; r++) {
            int m = m0 + quad * 4 + r;
            xdbl[(size_t)m * 48 + e] = acc[j][r];
        }
    }
}

// ---------------- K4b: dt GEMM (K=16) + softplus -> dt (bf16) ----------------
__global__ __launch_bounds__(256) void k_dt(
    const float* __restrict__ xdbl, const bf16* __restrict__ dt_w,
    const bf16* __restrict__ dt_b, bf16* __restrict__ dt)
{
    __shared__ float xs[4][16];
    int row0 = blockIdx.x * 4;   // grid 3072
    int s = row0 >> 12;
    int t = threadIdx.x;
    if (t < 64) xs[t >> 4][t & 15] = xdbl[(size_t)(row0 + (t >> 4)) * 48 + (t & 15)];
    __syncthreads();
    for (int dd = 0; dd < 2; dd++) {
        int d = t + dd * 256;
        const uint4* wp = (const uint4*)(dt_w + ((size_t)s * NDI + d) * NDTR);
        float w[16]; dec8(wp[0], w); dec8(wp[1], w + 8);
        float bias = b2f(dt_b[s * NDI + d]);
        #pragma unroll
        for (int r = 0; r < 4; r++) {
            float a = bias;
            #pragma unroll
            for (int j = 0; j < 16; j++) a += w[j] * xs[r][j];
            a = (a > 20.0f) ? a : log1pf(__expf(a));   // softplus
            dt[(size_t)(row0 + r) * NDI + d] = __float2bfloat16(a);
        }
    }
}

// ---------------- K5a: chunk-local scan -> Hend, Pprod ----------------
__global__ __launch_bounds__(256) void k_scan1(
    const bf16* __restrict__ dt, const bf16* __restrict__ xa,
    const bf16* __restrict__ A_log, const float* __restrict__ xdbl,
    float* __restrict__ Hend, float* __restrict__ Pprod)
{
    __shared__ float Bs[LCH * NS];
    int bid = blockIdx.x;                 // 6 * NCH * 2
    int sb = bid / (NCH * 2);
    int rem = bid % (NCH * 2);
    int chunk = rem >> 1, dg = rem & 1;
    int s = sb >> 1;
    int t = threadIdx.x;
    int d = dg * 256 + t;
    int n0 = chunk * LCH;
    size_t rowbase = (size_t)sb * NN;
    #pragma unroll
    for (int i = 0; i < 2; i++) {    // stage B: 128 rows x 4 float4
        int idx = i * 256 + t;
        int row = idx >> 2, q = idx & 3;
        const float4* src = (const float4*)(xdbl + (rowbase + n0 + row) * 48 + 16);
        ((float4*)Bs)[idx] = src[q];
    }
    float A[16];
    {
        const uint4* ap = (const uint4*)(A_log + ((size_t)s * NDI + d) * NS);
        float al[8]; dec8(ap[0], al);
        #pragma unroll
        for (int i = 0; i < 8; i++) A[i] = -__expf(al[i]);
        dec8(ap[1], al);
        #pragma unroll
        for (int i = 0; i < 8; i++) A[8 + i] = -__expf(al[i]);
    }
    __syncthreads();
    float h[16], P[16];
    #pragma unroll
    for (int i = 0; i < 16; i++) { h[i] = 0.0f; P[i] = 1.0f; }
    const bf16* dtp = dt + (rowbase + n0) * NDI + d;
    const bf16* xap = xa + (rowbase + n0) * NDI + d;
    for (int nl = 0; nl < LCH; nl += 4) {
        float dtv[4], xav[4];
        #pragma unroll
        for (int j = 0; j < 4; j++) {
            dtv[j] = b2f(dtp[(size_t)(nl + j) * NDI]);
            xav[j] = b2f(xap[(size_t)(nl + j) * NDI]);
        }
        #pragma unroll
        for (int j = 0; j < 4; j++) {
            float bcom = dtv[j] * xav[j];
            const float4* br = (const float4*)&Bs[(nl + j) * NS];
            float4 b0 = br[0], b1 = br[1], b2 = br[2], b3 = br[3];
            float bv[16] = {b0.x,b0.y,b0.z,b0.w,b1.x,b1.y,b1.z,b1.w,
                            b2.x,b2.y,b2.z,b2.w,b3.x,b3.y,b3.z,b3.w};
            #pragma unroll
            for (int st = 0; st < 16; st++) {
                float dA = __expf(dtv[j] * A[st]);
                h[st] = dA * h[st] + bcom * bv[st];
                P[st] *= dA;
            }
        }
    }
    size_t base = ((size_t)(chunk * 6 + sb) * NS) * NDI + d;
    #pragma unroll
    for (int st = 0; st < 16; st++) {
        Hend[base + (size_t)st * NDI] = h[st];
        Pprod[base + (size_t)st * NDI] = P[st];
    }
}

// ---------------- K5b: serial prefix over chunk summaries (in place) ----------------
__global__ __launch_bounds__(256) void k_scomb(float* __restrict__ Hend, const float* __restrict__ Pprod)
{
    int idx = blockIdx.x * 256 + threadIdx.x;   // 3072 = 6 sb * 512 d
    int sb = idx >> 9, d = idx & (NDI - 1);
    float h[16];
    #pragma unroll
    for (int i = 0; i < 16; i++) h[i] = 0.0f;
    for (int c = 0; c < NCH; c++) {
        size_t base = ((size_t)(c * 6 + sb) * NS) * NDI + d;
        #pragma unroll
        for (int st = 0; st < 16; st++) {
            size_t g = base + (size_t)st * NDI;
            float He = Hend[g], Pp = Pprod[g];
            Hend[g] = h[st];                 // h_start for this chunk
            h[st] = He + Pp * h[st];
        }
    }
}

// ---------------- K5c: re-scan chunks from h_start, C-dot + gating -> y (bf16) ----------------
__global__ __launch_bounds__(256) void k_scan2(
    const bf16* __restrict__ dt, const bf16* __restrict__ xa, const bf16* __restrict__ z,
    const float* __restrict__ xdbl,
    const bf16* __restrict__ A_log, const bf16* __restrict__ Dp,
    const float* __restrict__ Hstart, bf16* __restrict__ y)
{
    __shared__ float Bs[LCH * NS], Cs[LCH * NS];
    int bid = blockIdx.x;
    int sb = bid / (NCH * 2);
    int rem = bid % (NCH * 2);
    int chunk = rem >> 1, dg = rem & 1;
    int s = sb >> 1;
    int t = threadIdx.x;
    int d = dg * 256 + t;
    int n0 = chunk * LCH;
    size_t rowbase = (size_t)sb * NN;
    #pragma unroll
    for (int i = 0; i < 2; i++) {
        int idx = i * 256 + t;
        int row = idx >> 2, q = idx & 3;
        const float4* srcB = (const float4*)(xdbl + (rowbase + n0 + row) * 48 + 16);
        const float4* srcC = (const float4*)(xdbl + (rowbase + n0 + row) * 48 + 32);
        ((float4*)Bs)[idx] = srcB[q];
        ((float4*)Cs)[idx] = srcC[q];
    }
    float A[16];
    {
        const uint4* ap = (const uint4*)(A_log + ((size_t)s * NDI + d) * NS);
        float al[8]; dec8(ap[0], al);
        #pragma unroll
        for (int i = 0; i < 8; i++) A[i] = -__expf(al[i]);
        dec8(ap[1], al);
        #pragma unroll
        for (int i = 0; i < 8; i++) A[8 + i] = -__expf(al[i]);
    }
    float Dpv = b2f(Dp[s * NDI + d]);
    float h[16];
    {
        size_t base = ((size_t)(chunk * 6 + sb) * NS) * NDI + d;
        #pragma unroll
        for (int st = 0; st < 16; st++) h[st] = Hstart[base + (size_t)st * NDI];
    }
    __syncthreads();
    const bf16* dtp = dt + (rowbase + n0) * NDI + d;
    const bf16* xap = xa + (rowbase + n0) * NDI + d;
    const bf16* zp  = z  + (rowbase + n0) * NDI + d;
    bf16* yp = y + (rowbase + n0) * NDI + d;
    for (int nl = 0; nl < LCH; nl += 4) {
        float dtv[4], xav[4], zv[4];
        #pragma unroll
        for (int j = 0; j < 4; j++) {
            dtv[j] = b2f(dtp[(size_t)(nl + j) * NDI]);
            xav[j] = b2f(xap[(size_t)(nl + j) * NDI]);
            zv[j]  = b2f(zp [(size_t)(nl + j) * NDI]);
        }
        #pragma unroll
        for (int j = 0; j < 4; j++) {
            float bcom = dtv[j] * xav[j];
            const float4* br = (const float4*)&Bs[(nl + j) * NS];
            const float4* cr = (const float4*)&Cs[(nl + j) * NS];
            float4 b0 = br[0], b1 = br[1], b2 = br[2], b3 = br[3];
            float4 c0 = cr[0], c1 = cr[1], c2 = cr[2], c3 = cr[3];
            float bv[16] = {b0.x,b0.y,b0.z,b0.w,b1.x,b1.y,b1.z,b1.w,
                            b2.x,b2.y,b2.z,b2.w,b3.x,b3.y,b3.z,b3.w};
            float cv[16] = {c0.x,c0.y,c0.z,c0.w,c1.x,c1.y,c1.z,c1.w,
                            c2.x,c2.y,c2.z,c2.w,c3.x,c3.y,c3.z,c3.w};
            float yacc = 0.0f;
            #pragma unroll
            for (int st = 0; st < 16; st++) {
                float dA = __expf(dtv[j] * A[st]);
                h[st] = dA * h[st] + bcom * bv[st];
                yacc += h[st] * cv[st];
            }
            float yv = yacc + xav[j] * Dpv;
            float zz = zv[j];
            yv *= zz / (1.0f + __expf(-zz));
            yp[(size_t)(nl + j) * NDI] = __float2bfloat16(yv);
        }
    }
}

// ---------------- K6: out_proj GEMM (MFMA) + residual -> proc (bf16) ----------------
// grid 192 m-blocks x 4 e-blocks
__global__ __launch_bounds__(256) void k_outproj_mfma(
    const bf16* __restrict__ y, const bf16* __restrict__ out_w,
    const bf16* __restrict__ e_, const bf16* __restrict__ bl, const bf16* __restrict__ sp,
    bf16* __restrict__ proc)
{
    int bid = blockIdx.x;
    int bm = bid >> 2, be = bid & 3;
    int t = threadIdx.x;
    int w = t >> 6, l = t & 63;
    int quad = l >> 4, lan = l & 15;
    int m0 = bm * 64 + w * 16;
    int e0 = be * 64;
    int s = m0 >> 12;
    const bf16* W = out_w + (size_t)s * ND * NDI;
    f32x4 acc[4];
    #pragma unroll
    for (int j = 0; j < 4; j++) acc[j] = (f32x4){0.f, 0.f, 0.f, 0.f};
    const bf16* arow = y + (size_t)(m0 + lan) * NDI + quad * 8;
    const bf16* brow = W + (size_t)(e0 + lan) * NDI + quad * 8;
    #pragma unroll 2
    for (int kk = 0; kk < 16; kk++) {
        bf16x8 a = *(const bf16x8*)(arow + kk * 32);
        #pragma unroll
        for (int j = 0; j < 4; j++) {
            bf16x8 b = *(const bf16x8*)(brow + (size_t)j * 16 * NDI + kk * 32);
            acc[j] = __builtin_amdgcn_mfma_f32_16x16x32_bf16(a, b, acc[j], 0, 0, 0);
        }
    }
    const bf16* xin = (s == 0) ? e_ : ((s == 1) ? bl : sp);
    #pragma unroll
    for (int j = 0; j < 4; j++) {
        int e = e0 + j * 16 + lan;
        #pragma unroll
        for (int r = 0; r < 4; r++) {
            int m = m0 + quad * 4 + r;         // global row: sb*2048+n
            int b = (m >> 11) & 1, n = m & (NN - 1);
            float res = b2f(xin[((size_t)(b * NN + n)) * ND + e]);
            proc[(size_t)m * ND + e] = __float2bfloat16(acc[j][r] + res);
        }
    }
}

// ---------------- K7: mean-pool over N -> pooled (B,768) fp32 ----------------
__global__ __launch_bounds__(256) void k_pool(const bf16* __restrict__ proc, float* __restrict__ pooled)
{
    int e = blockIdx.x % 768, b = blockIdx.x / 768;
    int s = e >> 8, d = e & 255;
    const bf16* p = proc + ((size_t)(s * NB + b) * NN) * ND + d;
    float acc = 0.0f;
    for (int n = threadIdx.x; n < NN; n += 256) acc += b2f(p[(size_t)n * ND]);
    #pragma unroll
    for (int m = 1; m < 64; m <<= 1) acc += __shfl_xor(acc, m);
    __shared__ float r[4];
    if ((threadIdx.x & 63) == 0) r[threadIdx.x >> 6] = acc;
    __syncthreads();
    if (threadIdx.x == 0) pooled[b * 768 + e] = (r[0] + r[1] + r[2] + r[3]) * (1.0f / NN);
}

// ---------------- K8: gelu MLP + double softmax -> coeffs (B,3) fp32 ----------------
__global__ __launch_bounds__(256) void k_coeff(
    const float* __restrict__ pooled,
    const bf16* __restrict__ agg_w1, const bf16* __restrict__ agg_b1,
    const bf16* __restrict__ agg_w2, const bf16* __restrict__ agg_b2,
    const bf16* __restrict__ temp, float* __restrict__ coeffs)
{
    __shared__ float hb[256];
    __shared__ float lg[3];
    int t = threadIdx.x;
    for (int b = 0; b < NB; b++) {
        float a = b2f(agg_b1[t]);
        const uint4* wp = (const uint4*)(agg_w1 + (size_t)t * 768);
        for (int k8 = 0; k8 < 96; k8++) {
            float w[8]; dec8(wp[k8], w);
            const float* pp = pooled + b * 768 + k8 * 8;
            #pragma unroll
            for (int j = 0; j < 8; j++) a += w[j] * pp[j];
        }
        float x = a;
        float inner = 0.7978845608028654f * (x + 0.044715f * x * x * x);
        hb[t] = 0.5f * x * (1.0f + tanhf(inner));
        __syncthreads();
        if (t < 3) {
            float l = b2f(agg_b2[t]);
            const bf16* w2 = agg_w2 + t * 256;
            for (int d2 = 0; d2 < 256; d2++) l += b2f(w2[d2]) * hb[d2];
            lg[t] = l;
        }
        __syncthreads();
        if (t == 0) {
            float m = fmaxf(lg[0], fmaxf(lg[1], lg[2]));
            float e0 = __expf(lg[0] - m), e1 = __expf(lg[1] - m), e2 = __expf(lg[2] - m);
            float iS = 1.0f / (e0 + e1 + e2);
            float c0 = e0 * iS, c1 = e1 * iS, c2 = e2 * iS;
            float tt = b2f(temp[0]) + 1e-6f;
            float m2 = fmaxf(c0, fmaxf(c1, c2)) / tt;
            e0 = __expf(c0 / tt - m2); e1 = __expf(c1 / tt - m2); e2 = __expf(c2 / tt - m2);
            iS = 1.0f / (e0 + e1 + e2);
            coeffs[b * 3 + 0] = e0 * iS;
            coeffs[b * 3 + 1] = e1 * iS;
            coeffs[b * 3 + 2] = e2 * iS;
        }
        __syncthreads();
    }
}

// ---------------- K9: final proj GEMM (MFMA) + weighted residual -> d_out ----------------
// A = multi (gathered from proc), K=768; grid 64 m-blocks x 4 e-blocks
__global__ __launch_bounds__(256) void k_final_mfma(
    const bf16* __restrict__ proc, const bf16* __restrict__ proj_w,
    const bf16* __restrict__ proj_b, const float* __restrict__ coeffs,
    const int* __restrict__ flag, void* __restrict__ out)
{
    int bid = blockIdx.x;
    int bm = bid >> 2, be = bid & 3;
    int t = threadIdx.x;
    int w = t >> 6, l = t & 63;
    int quad = l >> 4, lan = l & 15;
    int m0 = bm * 64 + w * 16;        // rows over B*N (4096)
    int e0 = be * 64;
    f32x4 acc[4];
    #pragma unroll
    for (int j = 0; j < 4; j++) acc[j] = (f32x4){0.f, 0.f, 0.f, 0.f};
    int mA = m0 + lan;
    int bA = mA >> 11, nA = mA & (NN - 1);
    size_t abase = ((size_t)(bA * NN + nA)) * ND;   // + s*1048576 + kd
    const bf16* brow = proj_w + (size_t)(e0 + lan) * 768 + quad * 8;
    #pragma unroll 2
    for (int kk = 0; kk < 24; kk++) {
        int k0 = kk * 32 + quad * 8;
        int sA = k0 >> 8, kd = k0 & 255;
        bf16x8 a = *(const bf16x8*)(proc + abase + (size_t)sA * (NB * NN * ND) + kd);
        #pragma unroll
        for (int j = 0; j < 4; j++) {
            bf16x8 b = *(const bf16x8*)(brow + (size_t)j * 16 * 768 + kk * 32);
            acc[j] = __builtin_amdgcn_mfma_f32_16x16x32_bf16(a, b, acc[j], 0, 0, 0);
        }
    }
    #pragma unroll
    for (int j = 0; j < 4; j++) {
        int e = e0 + j * 16 + lan;
        float pb = b2f(proj_b[e]);
        #pragma unroll
        for (int r = 0; r < 4; r++) {
            int m = m0 + quad * 4 + r;
            int b = m >> 11, n = m & (NN - 1);
            float c0 = coeffs[b * 3], c1 = coeffs[b * 3 + 1], c2 = coeffs[b * 3 + 2];
            size_t pbase = ((size_t)(b * NN + n)) * ND + e;
            float wres = c0 * b2f(proc[pbase])
                       + c1 * b2f(proc[pbase + (size_t)1 * NB * NN * ND])
                       + c2 * b2f(proc[pbase + (size_t)2 * NB * NN * ND]);
            float v = acc[j][r] + pb + wres;
            if (flag[0]) ((float*)out)[(size_t)m * ND + e] = v;
            else         ((bf16*)out)[(size_t)m * ND + e] = __float2bfloat16(v);
        }
    }
}

extern "C" void kernel_launch(void* const* d_in, const int* in_sizes, int n_in,
                              void* d_out, int out_size, void* d_ws, size_t ws_size,
                              hipStream_t stream)
{
    // ---- workspace layout (bytes), total ~71.5 MB ----
    char* w8 = (char*)d_ws;
    int*   flagp   = (int*)(w8);                    // 16 B
    bf16*  cvt     = (bf16*)(w8 + 16);              // 9,710,144 B
    bf16*  xn      = (bf16*)(w8 + 9710160);         // 6,291,456 B (reused as proc)
    bf16*  xcb     = (bf16*)(w8 + 16001616);        // 12,582,912 B (xc, then y)
    bf16*  zb      = (bf16*)(w8 + 28584528);
    bf16*  xab     = (bf16*)(w8 + 41167440);
    bf16*  dtb     = (bf16*)(w8 + 53750352);
    float* xdblb   = (float*)(w8 + 66333264);       // 12288*48 f32 = 2,359,296 B
    float* pooledb = (float*)(w8 + 68692560);       // 6,144 B
    float* coeffsb = (float*)(w8 + 68698704);       // 32 B
    float* Hendb   = (float*)(w8 + 68698736);       // 3,145,728 B (then h_start)
    float* Pprodb  = (float*)(w8 + 71844464);       // 3,145,728 B -> end 74,990,192
    bf16*  procb   = xn;                            // xn dead after k_inproj

    const bf16* c_edge   = cvt + 0;
    const bf16* c_blob   = cvt + 1048576;
    const bf16* c_spec   = cvt + 2097152;
    const bf16* c_inw    = cvt + 3145728;
    const bf16* c_outw   = cvt + 3932160;
    const bf16* c_xpw    = cvt + 4325376;
    const bf16* c_dtw    = cvt + 4399104;
    const bf16* c_alog   = cvt + 4423680;
    const bf16* c_agg1   = cvt + 4448256;
    const bf16* c_prjw   = cvt + 4644864;
    const bf16* c_convw  = cvt + 4841472;
    const bf16* c_nrmw   = cvt + 4847616;
    const bf16* c_nrmb   = cvt + 4848384;
    const bf16* c_convb  = cvt + 4849152;
    const bf16* c_dtb    = cvt + 4850688;
    const bf16* c_dp     = cvt + 4852224;
    const bf16* c_agb1   = cvt + 4853760;
    const bf16* c_agw2   = cvt + 4854016;
    const bf16* c_agb2   = cvt + 4854784;
    const bf16* c_prjb   = cvt + 4854800;
    const bf16* c_temp   = cvt + 4855056;

    k_detect<<<1, 64, 0, stream>>>((const unsigned*)d_in[3], flagp);
    CvtArgs ca;
    for (int i = 0; i < 21; i++) ca.s[i] = d_in[i];
    k_convert<<<(4855044 + 255) / 256, 256, 0, stream>>>(ca, flagp, cvt);

    k_layernorm<<<6 * NN, 256, 0, stream>>>(c_edge, c_blob, c_spec, c_nrmw, c_nrmb, xn);
    k_inproj_mfma<<<192 * 16, 256, 0, stream>>>(xn, c_inw, xcb, zb);
    k_conv<<<6 * NN * NDI / 256, 256, 0, stream>>>(xcb, c_convw, c_convb, xab);
    k_xproj_mfma<<<192, 256, 0, stream>>>(xab, c_xpw, xdblb);
    k_dt<<<3072, 256, 0, stream>>>(xdblb, c_dtw, c_dtb, dtb);
    k_scan1<<<6 * NCH * 2, 256, 0, stream>>>(dtb, xab, c_alog, xdblb, Hendb, Pprodb);
    k_scomb<<<12, 256, 0, stream>>>(Hendb, Pprodb);
    k_scan2<<<6 * NCH * 2, 256, 0, stream>>>(dtb, xab, zb, xdblb, c_alog, c_dp, Hendb, xcb);
    k_outproj_mfma<<<192 * 4, 256, 0, stream>>>(xcb, c_outw, c_edge, c_blob, c_spec, procb);
    k_pool<<<NB * 768, 256, 0, stream>>>(procb, pooledb);
    k_coeff<<<1, 256, 0, stream>>>(pooledb, c_agg1, c_agb1, c_agw2, c_agb2, c_temp, coeffsb);
    k_final_mfma<<<64 * 4, 256, 0, stream>>>(procb, c_prjw, c_prjb, coeffsb, flagp, d_out);
}

// Round 6
// 385.292 us; speedup vs baseline: 2.9960x; 1.1664x over previous
//
#include <hip/hip_runtime.h>
#include <hip/hip_bf16.h>

#define NB 2
#define NN 2048
#define ND 256
#define NS 16
#define NDC 4
#define NDI 512
#define NDTR 16
#define LCH 128   // chunk length for parallel scan
#define NCH 16    // number of chunks (LCH*NCH == NN)

typedef __hip_bfloat16 bf16;
typedef __attribute__((ext_vector_type(8))) __bf16 bf16x8;
typedef __attribute__((ext_vector_type(4))) float f32x4;

__device__ __forceinline__ float b2f(bf16 h) { return __bfloat162float(h); }

__device__ __forceinline__ void dec8(const uint4 u, float w[8]) {
    union { unsigned u; float f; } c;
    c.u = u.x << 16;          w[0] = c.f;
    c.u = u.x & 0xffff0000u;  w[1] = c.f;
    c.u = u.y << 16;          w[2] = c.f;
    c.u = u.y & 0xffff0000u;  w[3] = c.f;
    c.u = u.z << 16;          w[4] = c.f;
    c.u = u.z & 0xffff0000u;  w[5] = c.f;
    c.u = u.w << 16;          w[6] = c.f;
    c.u = u.w & 0xffff0000u;  w[7] = c.f;
}

// ---------------- K0a: detect input dtype (fp32 vs bf16) ----------------
__global__ void k_detect(const unsigned* __restrict__ nw_raw, int* __restrict__ flag)
{
    if (threadIdx.x == 0 && blockIdx.x == 0) {
        unsigned v = nw_raw[0];
        flag[0] = ((v & 0xFFFFu) == 0u) ? 1 : 0;   // 1 = inputs are fp32
    }
}

// ---------------- K0b: convert/copy all inputs to bf16 in workspace ----------------
struct CvtArgs { const void* s[21]; };
__device__ __constant__ const int seg_cum[22] = {
    0, 1048576, 2097152, 3145728, 3146496, 3147264, 3933696, 3939840,
    3941376, 4015104, 4039680, 4041216, 4065792, 4067328, 4460544, 4460545,
    4657153, 4657409, 4658177, 4658180, 4854788, 4855044 };
__device__ __constant__ const int seg_dst[21] = {
    0,        1048576,  2097152,  4847616, 4848384, 3145728, 4841472, 4849152, 4325376,
    4399104,  4850688,  4423680,  4852224, 3932160, 4855056, 4448256, 4853760, 4854016,
    4854784,  4644864,  4854800 };

__global__ __launch_bounds__(256) void k_convert(CvtArgs a, const int* __restrict__ flag,
                                                 bf16* __restrict__ dst)
{
    int idx = blockIdx.x * 256 + threadIdx.x;
    if (idx >= 4855044) return;
    int seg = 0;
    #pragma unroll
    for (int i = 1; i < 21; i++) if (idx >= seg_cum[i]) seg = i;
    int off = idx - seg_cum[seg];
    int f = flag[0];
    bf16 v;
    if (f) v = __float2bfloat16(((const float*)a.s[seg])[off]);
    else   v = ((const bf16*)a.s[seg])[off];
    dst[seg_dst[seg] + off] = v;
}

// ---------------- K1: layernorm per row -> xn (bf16) ----------------
__global__ __launch_bounds__(256) void k_layernorm(
    const bf16* __restrict__ e, const bf16* __restrict__ bl, const bf16* __restrict__ sp,
    const bf16* __restrict__ nw, const bf16* __restrict__ nb, bf16* __restrict__ xn)
{
    int row = blockIdx.x;            // sb*NN + n, sb = s*NB + b
    int sb = row >> 11, n = row & (NN - 1);
    int s = sb >> 1, b = sb & 1;
    const bf16* xin = (s == 0) ? e : ((s == 1) ? bl : sp);
    int t = threadIdx.x;
    float v = b2f(xin[((b << 11) + n) * ND + t]);
    float s1 = v, s2 = v * v;
    #pragma unroll
    for (int m = 1; m < 64; m <<= 1) { s1 += __shfl_xor(s1, m); s2 += __shfl_xor(s2, m); }
    __shared__ float r1[4], r2[4];
    int w = t >> 6;
    if ((t & 63) == 0) { r1[w] = s1; r2[w] = s2; }
    __syncthreads();
    float mean = (r1[0] + r1[1] + r1[2] + r1[3]) * (1.0f / ND);
    float ms   = (r2[0] + r2[1] + r2[2] + r2[3]) * (1.0f / ND);
    float inv = rsqrtf(ms - mean * mean + 1e-5f);
    float wv = b2f(nw[s * ND + t]), bv = b2f(nb[s * ND + t]);
    xn[row * ND + t] = __float2bfloat16((v - mean) * inv * wv + bv);
}

// ---------------- K2: in_proj tiled MFMA GEMM -> xc, z ----------------
// block: 128m x 64n, 4 waves (each 32m x 64n, acc 2x4), BK=64, K=256
__global__ __launch_bounds__(256) void k_inproj_t(
    const bf16* __restrict__ xn, const bf16* __restrict__ in_w,
    bf16* __restrict__ xc, bf16* __restrict__ z)
{
    __shared__ bf16 As[128 * 72];
    __shared__ bf16 Bs[64 * 72];
    int bid = blockIdx.x;
    int bm = bid >> 4, bn = bid & 15;          // 96 x 16
    int m0 = bm * 128, e0 = bn * 64;
    int s = m0 >> 12;
    const bf16* W = in_w + (size_t)s * (2 * NDI) * ND;
    int t = threadIdx.x;
    int w = t >> 6, l = t & 63;
    int quad = l >> 4, lan = l & 15;
    f32x4 acc[2][4];
    #pragma unroll
    for (int mi = 0; mi < 2; mi++)
        #pragma unroll
        for (int j = 0; j < 4; j++) acc[mi][j] = (f32x4){0.f, 0.f, 0.f, 0.f};
    for (int kc0 = 0; kc0 < 256; kc0 += 64) {
        __syncthreads();
        #pragma unroll
        for (int i = 0; i < 4; i++) {            // A: 128x64 = 1024 x bf16x8
            int li = i * 256 + t;
            int row = li >> 3, col = (li & 7) * 8;
            *(uint4*)&As[row * 72 + col] =
                *(const uint4*)(xn + (size_t)(m0 + row) * ND + kc0 + col);
        }
        #pragma unroll
        for (int i = 0; i < 2; i++) {            // B: 64x64 = 512 x bf16x8
            int li = i * 256 + t;
            int row = li >> 3, col = (li & 7) * 8;
            *(uint4*)&Bs[row * 72 + col] =
                *(const uint4*)(W + (size_t)(e0 + row) * ND + kc0 + col);
        }
        __syncthreads();
        #pragma unroll
        for (int kc = 0; kc < 64; kc += 32) {
            bf16x8 af[2], bf[4];
            #pragma unroll
            for (int mi = 0; mi < 2; mi++)
                af[mi] = *(const bf16x8*)&As[(w * 32 + mi * 16 + lan) * 72 + kc + quad * 8];
            #pragma unroll
            for (int j = 0; j < 4; j++)
                bf[j] = *(const bf16x8*)&Bs[(j * 16 + lan) * 72 + kc + quad * 8];
            #pragma unroll
            for (int mi = 0; mi < 2; mi++)
                #pragma unroll
                for (int j = 0; j < 4; j++)
                    acc[mi][j] = __builtin_amdgcn_mfma_f32_16x16x32_bf16(af[mi], bf[j], acc[mi][j], 0, 0, 0);
        }
    }
    bf16* dst = (e0 < NDI) ? xc : z;
    int ebase = e0 & (NDI - 1);
    #pragma unroll
    for (int mi = 0; mi < 2; mi++) {
        #pragma unroll
        for (int j = 0; j < 4; j++) {
            int ec = ebase + j * 16 + lan;
            #pragma unroll
            for (int r = 0; r < 4; r++) {
                int m = m0 + w * 32 + mi * 16 + quad * 4 + r;
                dst[(size_t)m * NDI + ec] = __float2bfloat16(acc[mi][j][r]);
            }
        }
    }
}

// ---------------- K3: causal depthwise conv (DC=4) + silu -> xa, vectorized x8 ----------------
__global__ __launch_bounds__(256) void k_conv(
    const bf16* __restrict__ xc, const bf16* __restrict__ conv_w,
    const bf16* __restrict__ conv_b, bf16* __restrict__ xa)
{
    int idx = blockIdx.x * 256 + threadIdx.x;   // over 6*2048*512/8 = 786432
    int d8 = (idx & 63) * 8;
    int rn = idx >> 6;                          // sb*NN + n
    int n = rn & (NN - 1);
    int sb = rn >> 11;
    int s = sb >> 1;
    // taps: w[j][k], 8 channels x 4 taps, contiguous 32 bf16
    const uint4* cwp = (const uint4*)(conv_w + ((size_t)s * NDI + d8) * NDC);
    float cwf[32];
    dec8(cwp[0], cwf); dec8(cwp[1], cwf + 8); dec8(cwp[2], cwf + 16); dec8(cwp[3], cwf + 24);
    float bias[8];
    dec8(*(const uint4*)(conv_b + (size_t)s * NDI + d8), bias);
    size_t g = (size_t)rn * NDI + d8;
    float xv[4][8];   // xv[tau] = x[n-tau]
    #pragma unroll
    for (int tau = 0; tau < 4; tau++) {
        if (n >= tau) dec8(*(const uint4*)(xc + g - (size_t)tau * NDI), xv[tau]);
        else
            #pragma unroll
            for (int j = 0; j < 8; j++) xv[tau][j] = 0.0f;
    }
    union { bf16 h[8]; uint4 u; } o;
    #pragma unroll
    for (int j = 0; j < 8; j++) {
        float a = bias[j];
        #pragma unroll
        for (int k = 0; k < 4; k++) a += cwf[j * 4 + k] * xv[3 - k][j];
        a = a / (1.0f + __expf(-a));
        o.h[j] = __float2bfloat16(a);
    }
    *(uint4*)(xa + g) = o.u;
}

// ---------------- K4a: x_proj tiled MFMA -> xdbl fp32 [12288][48] ----------------
// block: 128m x 48n, BK=64, K=512; grid 96
__global__ __launch_bounds__(256) void k_xproj_t(
    const bf16* __restrict__ xa, const bf16* __restrict__ xproj_w,
    float* __restrict__ xdbl)
{
    __shared__ bf16 As[128 * 72];
    __shared__ bf16 Bs[48 * 72];
    int bm = blockIdx.x;
    int m0 = bm * 128;
    int s = m0 >> 12;
    const bf16* W = xproj_w + (size_t)s * 48 * NDI;
    int t = threadIdx.x;
    int w = t >> 6, l = t & 63;
    int quad = l >> 4, lan = l & 15;
    f32x4 acc[2][3];
    #pragma unroll
    for (int mi = 0; mi < 2; mi++)
        #pragma unroll
        for (int j = 0; j < 3; j++) acc[mi][j] = (f32x4){0.f, 0.f, 0.f, 0.f};
    for (int kc0 = 0; kc0 < 512; kc0 += 64) {
        __syncthreads();
        #pragma unroll
        for (int i = 0; i < 4; i++) {
            int li = i * 256 + t;
            int row = li >> 3, col = (li & 7) * 8;
            *(uint4*)&As[row * 72 + col] =
                *(const uint4*)(xa + (size_t)(m0 + row) * NDI + kc0 + col);
        }
        {
            int li = t;                          // 48x64 = 384 x bf16x8
            if (li < 384) {
                int row = li >> 3, col = (li & 7) * 8;
                *(uint4*)&Bs[row * 72 + col] =
                    *(const uint4*)(W + (size_t)row * NDI + kc0 + col);
            } else if (li < 512) {
                int li2 = li + 128;              // covers 384..511 -> not needed
            }
        }
        {
            int li = 256 + t;
            if (li < 384) {
                int row = li >> 3, col = (li & 7) * 8;
                *(uint4*)&Bs[row * 72 + col] =
                    *(const uint4*)(W + (size_t)row * NDI + kc0 + col);
            }
        }
        __syncthreads();
        #pragma unroll
        for (int kc = 0; kc < 64; kc += 32) {
            bf16x8 af[2], bf[3];
            #pragma unroll
            for (int mi = 0; mi < 2; mi++)
                af[mi] = *(const bf16x8*)&As[(w * 32 + mi * 16 + lan) * 72 + kc + quad * 8];
            #pragma unroll
            for (int j = 0; j < 3; j++)
                bf[j] = *(const bf16x8*)&Bs[(j * 16 + lan) * 72 + kc + quad * 8];
            #pragma unroll
            for (int mi = 0; mi < 2; mi++)
                #pragma unroll
                for (int j = 0; j < 3; j++)
                    acc[mi][j] = __builtin_amdgcn_mfma_f32_16x16x32_bf16(af[mi], bf[j], acc[mi][j], 0, 0, 0);
        }
    }
    #pragma unroll
    for (int mi = 0; mi < 2; mi++) {
        #pragma unroll
        for (int j = 0; j < 3; j++) {
            int e = j * 16 + lan;
            #pragma unroll
            for (int r = 0; r < 4; r++) {
                int m = m0 + w * 32 + mi * 16 + quad * 4 + r;
                xdbl[(size_t)m * 48 + e] = acc[mi][j][r];
            }
        }
    }
}

// ---------------- K4b: dt GEMM (K=16) + softplus -> dt (bf16) ----------------
__global__ __launch_bounds__(256) void k_dt(
    const float* __restrict__ xdbl, const bf16* __restrict__ dt_w,
    const bf16* __restrict__ dt_b, bf16* __restrict__ dt)
{
    __shared__ float xs[4][16];
    int row0 = blockIdx.x * 4;   // grid 3072
    int s = row0 >> 12;
    int t = threadIdx.x;
    if (t < 64) xs[t >> 4][t & 15] = xdbl[(size_t)(row0 + (t >> 4)) * 48 + (t & 15)];
    __syncthreads();
    for (int dd = 0; dd < 2; dd++) {
        int d = t + dd * 256;
        const uint4* wp = (const uint4*)(dt_w + ((size_t)s * NDI + d) * NDTR);
        float w[16]; dec8(wp[0], w); dec8(wp[1], w + 8);
        float bias = b2f(dt_b[s * NDI + d]);
        #pragma unroll
        for (int r = 0; r < 4; r++) {
            float a = bias;
            #pragma unroll
            for (int j = 0; j < 16; j++) a += w[j] * xs[r][j];
            a = (a > 20.0f) ? a : log1pf(__expf(a));   // softplus
            dt[(size_t)(row0 + r) * NDI + d] = __float2bfloat16(a);
        }
    }
}

// ---------------- K5a: chunk-local scan -> Hend, Pprod ----------------
__global__ __launch_bounds__(256) void k_scan1(
    const bf16* __restrict__ dt, const bf16* __restrict__ xa,
    const bf16* __restrict__ A_log, const float* __restrict__ xdbl,
    float* __restrict__ Hend, float* __restrict__ Pprod)
{
    __shared__ float Bs[LCH * NS];
    int bid = blockIdx.x;                 // 6 * NCH * 2
    int sb = bid / (NCH * 2);
    int rem = bid % (NCH * 2);
    int chunk = rem >> 1, dg = rem & 1;
    int s = sb >> 1;
    int t = threadIdx.x;
    int d = dg * 256 + t;
    int n0 = chunk * LCH;
    size_t rowbase = (size_t)sb * NN;
    #pragma unroll
    for (int i = 0; i < 2; i++) {    // stage B: 128 rows x 4 float4
        int idx = i * 256 + t;
        int row = idx >> 2, q = idx & 3;
        const float4* src = (const float4*)(xdbl + (rowbase + n0 + row) * 48 + 16);
        ((float4*)Bs)[idx] = src[q];
    }
    float A[16];
    {
        const uint4* ap = (const uint4*)(A_log + ((size_t)s * NDI + d) * NS);
        float al[8]; dec8(ap[0], al);
        #pragma unroll
        for (int i = 0; i < 8; i++) A[i] = -__expf(al[i]);
        dec8(ap[1], al);
        #pragma unroll
        for (int i = 0; i < 8; i++) A[8 + i] = -__expf(al[i]);
    }
    __syncthreads();
    float h[16], P[16];
    #pragma unroll
    for (int i = 0; i < 16; i++) { h[i] = 0.0f; P[i] = 1.0f; }
    const bf16* dtp = dt + (rowbase + n0) * NDI + d;
    const bf16* xap = xa + (rowbase + n0) * NDI + d;
    for (int nl = 0; nl < LCH; nl += 4) {
        float dtv[4], xav[4];
        #pragma unroll
        for (int j = 0; j < 4; j++) {
            dtv[j] = b2f(dtp[(size_t)(nl + j) * NDI]);
            xav[j] = b2f(xap[(size_t)(nl + j) * NDI]);
        }
        #pragma unroll
        for (int j = 0; j < 4; j++) {
            float bcom = dtv[j] * xav[j];
            const float4* br = (const float4*)&Bs[(nl + j) * NS];
            float4 b0 = br[0], b1 = br[1], b2 = br[2], b3 = br[3];
            float bv[16] = {b0.x,b0.y,b0.z,b0.w,b1.x,b1.y,b1.z,b1.w,
                            b2.x,b2.y,b2.z,b2.w,b3.x,b3.y,b3.z,b3.w};
            #pragma unroll
            for (int st = 0; st < 16; st++) {
                float dA = __expf(dtv[j] * A[st]);
                h[st] = dA * h[st] + bcom * bv[st];
                P[st] *= dA;
            }
        }
    }
    size_t base = ((size_t)(chunk * 6 + sb) * NS) * NDI + d;
    #pragma unroll
    for (int st = 0; st < 16; st++) {
        Hend[base + (size_t)st * NDI] = h[st];
        Pprod[base + (size_t)st * NDI] = P[st];
    }
}

// ---------------- K5b: serial prefix over chunk summaries (in place) ----------------
__global__ __launch_bounds__(256) void k_scomb(float* __restrict__ Hend, const float* __restrict__ Pprod)
{
    int idx = blockIdx.x * 256 + threadIdx.x;   // 3072 = 6 sb * 512 d
    int sb = idx >> 9, d = idx & (NDI - 1);
    float h[16];
    #pragma unroll
    for (int i = 0; i < 16; i++) h[i] = 0.0f;
    for (int c = 0; c < NCH; c++) {
        size_t base = ((size_t)(c * 6 + sb) * NS) * NDI + d;
        #pragma unroll
        for (int st = 0; st < 16; st++) {
            size_t g = base + (size_t)st * NDI;
            float He = Hend[g], Pp = Pprod[g];
            Hend[g] = h[st];                 // h_start for this chunk
            h[st] = He + Pp * h[st];
        }
    }
}

// ---------------- K5c: re-scan chunks from h_start, C-dot + gating -> y (bf16) ----------------
__global__ __launch_bounds__(256) void k_scan2(
    const bf16* __restrict__ dt, const bf16* __restrict__ xa, const bf16* __restrict__ z,
    const float* __restrict__ xdbl,
    const bf16* __restrict__ A_log, const bf16* __restrict__ Dp,
    const float* __restrict__ Hstart, bf16* __restrict__ y)
{
    __shared__ float Bs[LCH * NS], Cs[LCH * NS];
    int bid = blockIdx.x;
    int sb = bid / (NCH * 2);
    int rem = bid % (NCH * 2);
    int chunk = rem >> 1, dg = rem & 1;
    int s = sb >> 1;
    int t = threadIdx.x;
    int d = dg * 256 + t;
    int n0 = chunk * LCH;
    size_t rowbase = (size_t)sb * NN;
    #pragma unroll
    for (int i = 0; i < 2; i++) {
        int idx = i * 256 + t;
        int row = idx >> 2, q = idx & 3;
        const float4* srcB = (const float4*)(xdbl + (rowbase + n0 + row) * 48 + 16);
        const float4* srcC = (const float4*)(xdbl + (rowbase + n0 + row) * 48 + 32);
        ((float4*)Bs)[idx] = srcB[q];
        ((float4*)Cs)[idx] = srcC[q];
    }
    float A[16];
    {
        const uint4* ap = (const uint4*)(A_log + ((size_t)s * NDI + d) * NS);
        float al[8]; dec8(ap[0], al);
        #pragma unroll
        for (int i = 0; i < 8; i++) A[i] = -__expf(al[i]);
        dec8(ap[1], al);
        #pragma unroll
        for (int i = 0; i < 8; i++) A[8 + i] = -__expf(al[i]);
    }
    float Dpv = b2f(Dp[s * NDI + d]);
    float h[16];
    {
        size_t base = ((size_t)(chunk * 6 + sb) * NS) * NDI + d;
        #pragma unroll
        for (int st = 0; st < 16; st++) h[st] = Hstart[base + (size_t)st * NDI];
    }
    __syncthreads();
    const bf16* dtp = dt + (rowbase + n0) * NDI + d;
    const bf16* xap = xa + (rowbase + n0) * NDI + d;
    const bf16* zp  = z  + (rowbase + n0) * NDI + d;
    bf16* yp = y + (rowbase + n0) * NDI + d;
    for (int nl = 0; nl < LCH; nl += 4) {
        float dtv[4], xav[4], zv[4];
        #pragma unroll
        for (int j = 0; j < 4; j++) {
            dtv[j] = b2f(dtp[(size_t)(nl + j) * NDI]);
            xav[j] = b2f(xap[(size_t)(nl + j) * NDI]);
            zv[j]  = b2f(zp [(size_t)(nl + j) * NDI]);
        }
        #pragma unroll
        for (int j = 0; j < 4; j++) {
            float bcom = dtv[j] * xav[j];
            const float4* br = (const float4*)&Bs[(nl + j) * NS];
            const float4* cr = (const float4*)&Cs[(nl + j) * NS];
            float4 b0 = br[0], b1 = br[1], b2 = br[2], b3 = br[3];
            float4 c0 = cr[0], c1 = cr[1], c2 = cr[2], c3 = cr[3];
            float bv[16] = {b0.x,b0.y,b0.z,b0.w,b1.x,b1.y,b1.z,b1.w,
                            b2.x,b2.y,b2.z,b2.w,b3.x,b3.y,b3.z,b3.w};
            float cv[16] = {c0.x,c0.y,c0.z,c0.w,c1.x,c1.y,c1.z,c1.w,
                            c2.x,c2.y,c2.z,c2.w,c3.x,c3.y,c3.z,c3.w};
            float yacc = 0.0f;
            #pragma unroll
            for (int st = 0; st < 16; st++) {
                float dA = __expf(dtv[j] * A[st]);
                h[st] = dA * h[st] + bcom * bv[st];
                yacc += h[st] * cv[st];
            }
            float yv = yacc + xav[j] * Dpv;
            float zz = zv[j];
            yv *= zz / (1.0f + __expf(-zz));
            yp[(size_t)(nl + j) * NDI] = __float2bfloat16(yv);
        }
    }
}

// ---------------- K6: out_proj tiled MFMA + residual -> proc ----------------
// block: 128m x 64n, BK=64, K=512; grid 96 x 4
__global__ __launch_bounds__(256) void k_outproj_t(
    const bf16* __restrict__ y, const bf16* __restrict__ out_w,
    const bf16* __restrict__ e_, const bf16* __restrict__ bl, const bf16* __restrict__ sp,
    bf16* __restrict__ proc)
{
    __shared__ bf16 As[128 * 72];
    __shared__ bf16 Bs[64 * 72];
    int bid = blockIdx.x;
    int bm = bid >> 2, bn = bid & 3;
    int m0 = bm * 128, e0 = bn * 64;
    int s = m0 >> 12;
    const bf16* W = out_w + (size_t)s * ND * NDI;
    int t = threadIdx.x;
    int w = t >> 6, l = t & 63;
    int quad = l >> 4, lan = l & 15;
    f32x4 acc[2][4];
    #pragma unroll
    for (int mi = 0; mi < 2; mi++)
        #pragma unroll
        for (int j = 0; j < 4; j++) acc[mi][j] = (f32x4){0.f, 0.f, 0.f, 0.f};
    for (int kc0 = 0; kc0 < 512; kc0 += 64) {
        __syncthreads();
        #pragma unroll
        for (int i = 0; i < 4; i++) {
            int li = i * 256 + t;
            int row = li >> 3, col = (li & 7) * 8;
            *(uint4*)&As[row * 72 + col] =
                *(const uint4*)(y + (size_t)(m0 + row) * NDI + kc0 + col);
        }
        #pragma unroll
        for (int i = 0; i < 2; i++) {
            int li = i * 256 + t;
            int row = li >> 3, col = (li & 7) * 8;
            *(uint4*)&Bs[row * 72 + col] =
                *(const uint4*)(W + (size_t)(e0 + row) * NDI + kc0 + col);
        }
        __syncthreads();
        #pragma unroll
        for (int kc = 0; kc < 64; kc += 32) {
            bf16x8 af[2], bf[4];
            #pragma unroll
            for (int mi = 0; mi < 2; mi++)
                af[mi] = *(const bf16x8*)&As[(w * 32 + mi * 16 + lan) * 72 + kc + quad * 8];
            #pragma unroll
            for (int j = 0; j < 4; j++)
                bf[j] = *(const bf16x8*)&Bs[(j * 16 + lan) * 72 + kc + quad * 8];
            #pragma unroll
            for (int mi = 0; mi < 2; mi++)
                #pragma unroll
                for (int j = 0; j < 4; j++)
                    acc[mi][j] = __builtin_amdgcn_mfma_f32_16x16x32_bf16(af[mi], bf[j], acc[mi][j], 0, 0, 0);
        }
    }
    const bf16* xin = (s == 0) ? e_ : ((s == 1) ? bl : sp);
    #pragma unroll
    for (int mi = 0; mi < 2; mi++) {
        #pragma unroll
        for (int j = 0; j < 4; j++) {
            int e = e0 + j * 16 + lan;
            #pragma unroll
            for (int r = 0; r < 4; r++) {
                int m = m0 + w * 32 + mi * 16 + quad * 4 + r;
                int b = (m >> 11) & 1, n = m & (NN - 1);
                float res = b2f(xin[((size_t)(b * NN + n)) * ND + e]);
                proc[(size_t)m * ND + e] = __float2bfloat16(acc[mi][j][r] + res);
            }
        }
    }
}

// ---------------- K7: mean-pool (coalesced partial sums + atomicAdd) ----------------
// grid 48: (sb, chunk of 256 rows); pooled must be zeroed beforehand
__global__ __launch_bounds__(256) void k_pool2(const bf16* __restrict__ proc, float* __restrict__ pooled)
{
    int bid = blockIdx.x;
    int sb = bid / 8, chunk = bid % 8;
    int s = sb >> 1, b = sb & 1;
    int t = threadIdx.x;
    size_t base = ((size_t)sb * NN + chunk * 256) * ND + t;
    float acc = 0.0f;
    for (int r = 0; r < 256; r++) acc += b2f(proc[base + (size_t)r * ND]);
    atomicAdd(&pooled[b * 768 + s * 256 + t], acc);
}

// ---------------- K8: gelu MLP + double softmax -> coeffs (B,3) fp32 ----------------
// pooled holds SUMS over N (divide by NN here)
__global__ __launch_bounds__(256) void k_coeff(
    const float* __restrict__ pooled,
    const bf16* __restrict__ agg_w1, const bf16* __restrict__ agg_b1,
    const bf16* __restrict__ agg_w2, const bf16* __restrict__ agg_b2,
    const bf16* __restrict__ temp, float* __restrict__ coeffs)
{
    __shared__ float hb[256];
    __shared__ float lg[3];
    int t = threadIdx.x;
    for (int b = 0; b < NB; b++) {
        float dot = 0.0f;
        const uint4* wp = (const uint4*)(agg_w1 + (size_t)t * 768);
        for (int k8 = 0; k8 < 96; k8++) {
            float w[8]; dec8(wp[k8], w);
            const float* pp = pooled + b * 768 + k8 * 8;
            #pragma unroll
            for (int j = 0; j < 8; j++) dot += w[j] * pp[j];
        }
        float x = b2f(agg_b1[t]) + dot * (1.0f / NN);
        float inner = 0.7978845608028654f * (x + 0.044715f * x * x * x);
        hb[t] = 0.5f * x * (1.0f + tanhf(inner));
        __syncthreads();
        if (t < 3) {
            float l = b2f(agg_b2[t]);
            const bf16* w2 = agg_w2 + t * 256;
            for (int d2 = 0; d2 < 256; d2++) l += b2f(w2[d2]) * hb[d2];
            lg[t] = l;
        }
        __syncthreads();
        if (t == 0) {
            float m = fmaxf(lg[0], fmaxf(lg[1], lg[2]));
            float e0 = __expf(lg[0] - m), e1 = __expf(lg[1] - m), e2 = __expf(lg[2] - m);
            float iS = 1.0f / (e0 + e1 + e2);
            float c0 = e0 * iS, c1 = e1 * iS, c2 = e2 * iS;
            float tt = b2f(temp[0]) + 1e-6f;
            float m2 = fmaxf(c0, fmaxf(c1, c2)) / tt;
            e0 = __expf(c0 / tt - m2); e1 = __expf(c1 / tt - m2); e2 = __expf(c2 / tt - m2);
            iS = 1.0f / (e0 + e1 + e2);
            coeffs[b * 3 + 0] = e0 * iS;
            coeffs[b * 3 + 1] = e1 * iS;
            coeffs[b * 3 + 2] = e2 * iS;
        }
        __syncthreads();
    }
}

// ---------------- K9: final proj tiled MFMA + weighted residual -> d_out ----------------
// block: 128m x 64n, BK=64, K=768 gathered over 3 proc segments; grid 32 x 4
__global__ __launch_bounds__(256) void k_final_t(
    const bf16* __restrict__ proc, const bf16* __restrict__ proj_w,
    const bf16* __restrict__ proj_b, const float* __restrict__ coeffs,
    const int* __restrict__ flag, void* __restrict__ out)
{
    __shared__ bf16 As[128 * 72];
    __shared__ bf16 Bs[64 * 72];
    int bid = blockIdx.x;
    int bm = bid >> 2, bn = bid & 3;
    int m0 = bm * 128, e0 = bn * 64;
    int b = m0 >> 11;                 // batch, const per block
    int nbase = m0 & (NN - 1);
    int t = threadIdx.x;
    int w = t >> 6, l = t & 63;
    int quad = l >> 4, lan = l & 15;
    f32x4 acc[2][4];
    #pragma unroll
    for (int mi = 0; mi < 2; mi++)
        #pragma unroll
        for (int j = 0; j < 4; j++) acc[mi][j] = (f32x4){0.f, 0.f, 0.f, 0.f};
    for (int kc0 = 0; kc0 < 768; kc0 += 64) {
        int sA = kc0 >> 8, kd0 = kc0 & 255;
        const bf16* Asrc = proc + ((size_t)(sA * NB + b) * NN + nbase) * ND + kd0;
        __syncthreads();
        #pragma unroll
        for (int i = 0; i < 4; i++) {
            int li = i * 256 + t;
            int row = li >> 3, col = (li & 7) * 8;
            *(uint4*)&As[row * 72 + col] = *(const uint4*)(Asrc + (size_t)row * ND + col);
        }
        #pragma unroll
        for (int i = 0; i < 2; i++) {
            int li = i * 256 + t;
            int row = li >> 3, col = (li & 7) * 8;
            *(uint4*)&Bs[row * 72 + col] =
                *(const uint4*)(proj_w + (size_t)(e0 + row) * 768 + kc0 + col);
        }
        __syncthreads();
        #pragma unroll
        for (int kc = 0; kc < 64; kc += 32) {
            bf16x8 af[2], bf[4];
            #pragma unroll
            for (int mi = 0; mi < 2; mi++)
                af[mi] = *(const bf16x8*)&As[(w * 32 + mi * 16 + lan) * 72 + kc + quad * 8];
            #pragma unroll
            for (int j = 0; j < 4; j++)
                bf[j] = *(const bf16x8*)&Bs[(j * 16 + lan) * 72 + kc + quad * 8];
            #pragma unroll
            for (int mi = 0; mi < 2; mi++)
                #pragma unroll
                for (int j = 0; j < 4; j++)
                    acc[mi][j] = __builtin_amdgcn_mfma_f32_16x16x32_bf16(af[mi], bf[j], acc[mi][j], 0, 0, 0);
        }
    }
    float c0 = coeffs[b * 3], c1 = coeffs[b * 3 + 1], c2 = coeffs[b * 3 + 2];
    int f = flag[0];
    #pragma unroll
    for (int mi = 0; mi < 2; mi++) {
        #pragma unroll
        for (int j = 0; j < 4; j++) {
            int e = e0 + j * 16 + lan;
            float pb = b2f(proj_b[e]);
            #pragma unroll
            for (int r = 0; r < 4; r++) {
                int m = m0 + w * 32 + mi * 16 + quad * 4 + r;
                int n = m & (NN - 1);
                size_t pbase = ((size_t)b * NN + n) * ND + e;
                float wres = c0 * b2f(proc[pbase])
                           + c1 * b2f(proc[pbase + (size_t)1 * NB * NN * ND])
                           + c2 * b2f(proc[pbase + (size_t)2 * NB * NN * ND]);
                float v = acc[mi][j][r] + pb + wres;
                if (f) ((float*)out)[(size_t)m * ND + e] = v;
                else   ((bf16*)out)[(size_t)m * ND + e] = __float2bfloat16(v);
            }
        }
    }
}

extern "C" void kernel_launch(void* const* d_in, const int* in_sizes, int n_in,
                              void* d_out, int out_size, void* d_ws, size_t ws_size,
                              hipStream_t stream)
{
    // ---- workspace layout (bytes), total ~75 MB ----
    char* w8 = (char*)d_ws;
    int*   flagp   = (int*)(w8);                    // 16 B
    bf16*  cvt     = (bf16*)(w8 + 16);              // 9,710,144 B
    bf16*  xn      = (bf16*)(w8 + 9710160);         // 6,291,456 B (reused as proc)
    bf16*  xcb     = (bf16*)(w8 + 16001616);        // 12,582,912 B (xc, then y)
    bf16*  zb      = (bf16*)(w8 + 28584528);
    bf16*  xab     = (bf16*)(w8 + 41167440);
    bf16*  dtb     = (bf16*)(w8 + 53750352);
    float* xdblb   = (float*)(w8 + 66333264);       // 12288*48 f32 = 2,359,296 B
    float* pooledb = (float*)(w8 + 68692560);       // 6,144 B
    float* coeffsb = (float*)(w8 + 68698704);       // 32 B
    float* Hendb   = (float*)(w8 + 68698736);       // 3,145,728 B (then h_start)
    float* Pprodb  = (float*)(w8 + 71844464);       // 3,145,728 B -> end 74,990,192
    bf16*  procb   = xn;                            // xn dead after k_inproj

    const bf16* c_edge   = cvt + 0;
    const bf16* c_blob   = cvt + 1048576;
    const bf16* c_spec   = cvt + 2097152;
    const bf16* c_inw    = cvt + 3145728;
    const bf16* c_outw   = cvt + 3932160;
    const bf16* c_xpw    = cvt + 4325376;
    const bf16* c_dtw    = cvt + 4399104;
    const bf16* c_alog   = cvt + 4423680;
    const bf16* c_agg1   = cvt + 4448256;
    const bf16* c_prjw   = cvt + 4644864;
    const bf16* c_convw  = cvt + 4841472;
    const bf16* c_nrmw   = cvt + 4847616;
    const bf16* c_nrmb   = cvt + 4848384;
    const bf16* c_convb  = cvt + 4849152;
    const bf16* c_dtb    = cvt + 4850688;
    const bf16* c_dp     = cvt + 4852224;
    const bf16* c_agb1   = cvt + 4853760;
    const bf16* c_agw2   = cvt + 4854016;
    const bf16* c_agb2   = cvt + 4854784;
    const bf16* c_prjb   = cvt + 4854800;
    const bf16* c_temp   = cvt + 4855056;

    k_detect<<<1, 64, 0, stream>>>((const unsigned*)d_in[3], flagp);
    CvtArgs ca;
    for (int i = 0; i < 21; i++) ca.s[i] = d_in[i];
    k_convert<<<(4855044 + 255) / 256, 256, 0, stream>>>(ca, flagp, cvt);
    hipMemsetAsync(pooledb, 0, 6144, stream);

    k_layernorm<<<6 * NN, 256, 0, stream>>>(c_edge, c_blob, c_spec, c_nrmw, c_nrmb, xn);
    k_inproj_t<<<96 * 16, 256, 0, stream>>>(xn, c_inw, xcb, zb);
    k_conv<<<6 * NN * NDI / 8 / 256, 256, 0, stream>>>(xcb, c_convw, c_convb, xab);
    k_xproj_t<<<96, 256, 0, stream>>>(xab, c_xpw, xdblb);
    k_dt<<<3072, 256, 0, stream>>>(xdblb, c_dtw, c_dtb, dtb);
    k_scan1<<<6 * NCH * 2, 256, 0, stream>>>(dtb, xab, c_alog, xdblb, Hendb, Pprodb);
    k_scomb<<<12, 256, 0, stream>>>(Hendb, Pprodb);
    k_scan2<<<6 * NCH * 2, 256, 0, stream>>>(dtb, xab, zb, xdblb, c_alog, c_dp, Hendb, xcb);
    k_outproj_t<<<96 * 4, 256, 0, stream>>>(xcb, c_outw, c_edge, c_blob, c_spec, procb);
    k_pool2<<<48, 256, 0, stream>>>(procb, pooledb);
    k_coeff<<<1, 256, 0, stream>>>(pooledb, c_agg1, c_agb1, c_agw2, c_agb2, c_temp, coeffsb);
    k_final_t<<<32 * 4, 256, 0, stream>>>(procb, c_prjw, c_prjb, coeffsb, flagp, d_out);
}